// Round 2
// baseline (710.778 us; speedup 1.0000x reference)
//
#include <hip/hip_runtime.h>
#include <math.h>

// ---------------------------------------------------------------------------
// Block_42167988912800: dual-stream transformer block on gfx950.
// B=16 S=1024 D=512 H=4 hd=128 MLP=1024, fp32 in/out, bf16 MFMA compute.
// R6: XCD-affine GEMM grid mapping.
// R7: GEMM K-loop: XOR-chunk LDS swizzle + double-buffered staging.
// R8: attn rework for occupancy: KVBLK 64->32 (LDS 64KB->32KB/block ->
//     4 blocks/CU instead of 2). Attn is LDS-read-bound (1 ds_read_b128 per
//     MFMA, 4x wave redundancy on K/V tiles => ~47us LDS floor vs 31us MFMA
//     floor at 93us measured): double the resident blocks to overlap the
//     serial QK->exp->PV chain across independent blocks. V swizzle at 4
//     chunks/row: chunk ^= (row>>1)&3 (spreads 64 lanes over 8 superbanks).
//     s_setprio(1) around MFMA clusters (T5).
// ---------------------------------------------------------------------------

#define SEQ   1024
#define DM    512
#define HDIM  128
#define MTOK  16384
#define MLPD  1024
#define SC2   ((float)(0.08838834764831845 * 1.4426950408889634))  // scale*log2e

typedef short bf16x8 __attribute__((ext_vector_type(8)));
typedef float f32x4  __attribute__((ext_vector_type(4)));
typedef float f32x16 __attribute__((ext_vector_type(16)));
typedef unsigned short us4 __attribute__((ext_vector_type(4)));

typedef unsigned int u32g __attribute__((address_space(1)));
typedef unsigned int u32l __attribute__((address_space(3)));

static __device__ __forceinline__ unsigned short f2b(float f) {
  union { float f; unsigned u; } v; v.f = f;
  unsigned r = v.u + 0x7FFFu + ((v.u >> 16) & 1u);
  return (unsigned short)(r >> 16);
}
static __device__ __forceinline__ float b2f(unsigned short h) {
  union { unsigned u; float f; } v; v.u = ((unsigned)h) << 16;
  return v.f;
}
// truncating pack: two floats -> two bf16 in one u32 [lo=a, hi=b]
static __device__ __forceinline__ unsigned pk2t(float a, float b) {
  union { float f; unsigned u; } va, vb; va.f = a; vb.f = b;
  return __builtin_amdgcn_perm(vb.u, va.u, 0x07060302u);
}
static __device__ __forceinline__ void gl_lds16(const void* g, void* l) {
  __builtin_amdgcn_global_load_lds((u32g*)g, (u32l*)l, 16, 0, 0);
}

// ---------------------------------------------------------------------------
// Prep: 12 weight transposes (fp32 [K][N] -> bf16 [N][K]) + 9-bias concat.
// ---------------------------------------------------------------------------
struct P12 { const float* p[12]; };
struct P9  { const float* p[9]; };

__global__ __launch_bounds__(256) void prep_kernel(P12 ws, P9 bs,
                                                   unsigned short* __restrict__ WT0,
                                                   unsigned short* __restrict__ W1t,
                                                   unsigned short* __restrict__ W2t,
                                                   float* __restrict__ bcc) {
  int bid = blockIdx.x;
  if (bid >= 3584) {
    int i = (bid - 3584) * 256 + threadIdx.x;
    if (i < 4608) bcc[i] = bs.p[i >> 9][i & 511];
    return;
  }
  __shared__ float t[32][33];
  const float* W; unsigned short* Wt; int K, N, tt;
  if (bid < 2560)      { int wi = bid >> 8; W = ws.p[wi]; Wt = WT0 + (size_t)wi * 262144; K = 512; N = 512; tt = bid & 255; }
  else if (bid < 3072) { W = ws.p[10]; Wt = W1t; K = 512;  N = 1024; tt = bid - 2560; }
  else                 { W = ws.p[11]; Wt = W2t; K = 1024; N = 512;  tt = bid - 3072; }
  int ntiles = N >> 5;
  int bx = tt % ntiles, by = tt / ntiles;
  int n0 = bx * 32, k0 = by * 32;
  int tx = threadIdx.x & 31, ty = threadIdx.x >> 5;
#pragma unroll
  for (int i = 0; i < 32; i += 8)
    t[ty + i][tx] = W[(size_t)(k0 + ty + i) * N + n0 + tx];
  __syncthreads();
#pragma unroll
  for (int i = 0; i < 32; i += 8)
    Wt[(size_t)(n0 + ty + i) * K + k0 + tx] = f2b(t[tx][ty + i]);
}

// ---------------------------------------------------------------------------
// Dual LayerNorm: one wave per row of 512, writes bf16.
// ---------------------------------------------------------------------------
__global__ __launch_bounds__(256) void ln_kernel(const float* __restrict__ X0,
                                                 const float* __restrict__ X1,
                                                 const float* __restrict__ g0w,
                                                 const float* __restrict__ b0w,
                                                 const float* __restrict__ g1w,
                                                 const float* __restrict__ b1w,
                                                 unsigned short* __restrict__ out0,
                                                 unsigned short* __restrict__ out1) {
  int idx  = blockIdx.x * 4 + (threadIdx.x >> 6);
  int sel  = idx >> 14;
  int row  = idx & 16383;
  const float* X = sel ? X1 : X0;
  const float* gw = sel ? g1w : g0w;
  const float* bw = sel ? b1w : b0w;
  unsigned short* outB = sel ? out1 : out0;
  int lane = threadIdx.x & 63;
  const float4* xr = (const float4*)(X + (size_t)row * DM);
  float4 a = xr[lane];
  float4 c = xr[lane + 64];
  float s  = a.x + a.y + a.z + a.w + c.x + c.y + c.z + c.w;
  float s2 = a.x*a.x + a.y*a.y + a.z*a.z + a.w*a.w
           + c.x*c.x + c.y*c.y + c.z*c.z + c.w*c.w;
#pragma unroll
  for (int off = 1; off < 64; off <<= 1) {
    s  += __shfl_xor(s,  off, 64);
    s2 += __shfl_xor(s2, off, 64);
  }
  float mean = s * (1.0f / 512.0f);
  float var  = s2 * (1.0f / 512.0f) - mean * mean;
  float rstd = rsqrtf(var + 1e-6f);
  const float4* gv = (const float4*)gw;
  const float4* bv = (const float4*)bw;
  float4 g1 = gv[lane], g2 = gv[lane + 64];
  float4 b1 = bv[lane], b2 = bv[lane + 64];
  us4 o1, o2;
  o1.x = f2b((a.x - mean) * rstd * g1.x + b1.x);
  o1.y = f2b((a.y - mean) * rstd * g1.y + b1.y);
  o1.z = f2b((a.z - mean) * rstd * g1.z + b1.z);
  o1.w = f2b((a.w - mean) * rstd * g1.w + b1.w);
  o2.x = f2b((c.x - mean) * rstd * g2.x + b2.x);
  o2.y = f2b((c.y - mean) * rstd * g2.y + b2.y);
  o2.z = f2b((c.z - mean) * rstd * g2.z + b2.z);
  o2.w = f2b((c.w - mean) * rstd * g2.w + b2.w);
  *(us4*)(outB + (size_t)row * DM + lane * 4)        = o1;
  *(us4*)(outB + (size_t)row * DM + (lane + 64) * 4) = o2;
}

// ---------------------------------------------------------------------------
// bf16 MFMA GEMM: C[M,N] = A[M,K] @ Bt[N,K]^T + bias (+res)(gelu)
// XCD-affine grid; double-buffered LDS; XOR-chunk swizzle both sides.
// RES: 0 none, 1 fp32 residual, 2 bf16 residual.
// OMODE 0: bf16 out. 1: fp32 out. 3: self-QKV. 4: cross-QKV.
// ---------------------------------------------------------------------------
template <int RES, bool GELU_ACT, int OMODE>
__global__ __launch_bounds__(256, 2) void gemm_kernel(const unsigned short* __restrict__ A,
                                                      const unsigned short* __restrict__ A1,
                                                      const unsigned short* __restrict__ Bt,
                                                      const float* __restrict__ bias,
                                                      const void* __restrict__ res,
                                                      float* __restrict__ outF,
                                                      unsigned short* __restrict__ outB,
                                                      unsigned short* __restrict__ outV,
                                                      int M, int N, int K) {
  int nT = N >> 7;
  int mT = M >> 7;
  int xcd = blockIdx.x & 7;
  int idx = blockIdx.x >> 3;
  int mPerX = mT >> 3;
  int q = idx / nT;
  int tm = xcd * mPerX + q;
  int tn = idx - q * nT;
  int m0 = tm << 7, n0 = tn << 7;
  int tid = threadIdx.x, lane = tid & 63, w = tid >> 6;
  int m16 = lane & 15, q4 = lane >> 4;
  int wr = (w & 1) << 6, wc = (w >> 1) << 6;
  __shared__ unsigned short Alds[2][128 * 64];
  __shared__ unsigned short Blds[2][128 * 64];
  f32x4 acc[4][4] = {};

  const unsigned short* Aeff = A;
  const unsigned short* Bteff = Bt;
  const float* biaseff = bias;
  if (OMODE == 3) {
    int half = tm >> 7;
    Bteff = Bt + (size_t)half * 3 * 262144;
    biaseff = bias + half * 1536;
  }
  if (OMODE == 4) {
    if (tn >= 4) Aeff = A1;
  }

  // staging: lane owns row = it*32 + w*8 + (lane>>3), LDS chunk lane&7;
  // swizzle folded into global source col: chunk ^= row&7. Reads XOR same.
  int srow = lane >> 3;
  int scol = ((lane & 7) ^ srow) << 3;
  const unsigned short* Ag = Aeff  + (size_t)(m0 + w * 8 + srow) * K + scol;
  const unsigned short* Bg = Bteff + (size_t)(n0 + w * 8 + srow) * K + scol;
  int ldst = w * 512;

#pragma unroll
  for (int it = 0; it < 4; ++it) {
    gl_lds16(Ag + (size_t)it * 32 * K, Alds[0] + it * 2048 + ldst);
    gl_lds16(Bg + (size_t)it * 32 * K, Blds[0] + it * 2048 + ldst);
  }

  int nk = K >> 6;
  for (int ks = 0; ks < nk; ++ks) {
    int cur = ks & 1, nxt = cur ^ 1;
    __syncthreads();
    if (ks + 1 < nk) {
      int k0n = (ks + 1) << 6;
#pragma unroll
      for (int it = 0; it < 4; ++it) {
        gl_lds16(Ag + (size_t)it * 32 * K + k0n, Alds[nxt] + it * 2048 + ldst);
        gl_lds16(Bg + (size_t)it * 32 * K + k0n, Blds[nxt] + it * 2048 + ldst);
      }
    }
    const unsigned short* Ar = Alds[cur];
    const unsigned short* Br = Blds[cur];
#pragma unroll
    for (int kk = 0; kk < 64; kk += 32) {
      bf16x8 af[4], bfr[4];
#pragma unroll
      for (int i = 0; i < 4; ++i) {
        int row = wr + i * 16 + m16;
        af[i] = *(const bf16x8*)(Ar + row * 64 + ((((kk >> 3) + q4) ^ (m16 & 7)) << 3));
      }
#pragma unroll
      for (int j = 0; j < 4; ++j) {
        int row = wc + j * 16 + m16;
        bfr[j] = *(const bf16x8*)(Br + row * 64 + ((((kk >> 3) + q4) ^ (m16 & 7)) << 3));
      }
#pragma unroll
      for (int i = 0; i < 4; ++i)
#pragma unroll
        for (int j = 0; j < 4; ++j)
          acc[i][j] = __builtin_amdgcn_mfma_f32_16x16x32_bf16(af[i], bfr[j], acc[i][j], 0, 0, 0);
    }
  }
  // epilogue: C/D layout col=lane&15, row=(lane>>4)*4+reg
  if (OMODE == 3 || OMODE == 4) {
    if (n0 < 1024) {
      int stride = (OMODE == 3) ? 1024 : 512;
      unsigned short* ob = outB;
      int coff = 0;
      if (OMODE == 4 && n0 >= 512) { ob = outB + (size_t)MTOK * 512; coff = 512; }
      float sc = (n0 < 512) ? SC2 : 1.0f;     // fold softmax scale into Q
#pragma unroll
      for (int i = 0; i < 4; ++i) {
#pragma unroll
        for (int r = 0; r < 4; ++r) {
          int row = m0 + wr + i * 16 + q4 * 4 + r;
#pragma unroll
          for (int j = 0; j < 4; ++j) {
            int col = n0 + wc + j * 16 + m16;
            ob[(size_t)row * stride + col - coff] = f2b((acc[i][j][r] + biaseff[col]) * sc);
          }
        }
      }
    } else {
#pragma unroll
      for (int i = 0; i < 4; ++i) {
        int row0 = m0 + wr + i * 16 + q4 * 4;
        int s = row0 & 1023, bl = row0 >> 10;
        // key-permutation sigma: swap bit2 <-> bit3 of seq index (4-aligned
        // groups keep their us4 contiguity). PV contracts over this order.
        s = (s & ~12) | ((s & 4) << 1) | ((s & 8) >> 1);
#pragma unroll
        for (int j = 0; j < 4; ++j) {
          int col = n0 + wc + j * 16 + m16;
          int hh = (col - 1024) >> 7, hd = col & 127;
          float bb = biaseff[col];
          us4 pkv;
          pkv.x = f2b(acc[i][j][0] + bb);
          pkv.y = f2b(acc[i][j][1] + bb);
          pkv.z = f2b(acc[i][j][2] + bb);
          pkv.w = f2b(acc[i][j][3] + bb);
          *(us4*)(outV + (((size_t)(bl * 4 + hh)) * HDIM + hd) * SEQ + s) = pkv;
        }
      }
    }
  } else {
#pragma unroll
    for (int i = 0; i < 4; ++i) {
#pragma unroll
      for (int r = 0; r < 4; ++r) {
        int row = m0 + wr + i * 16 + q4 * 4 + r;
#pragma unroll
        for (int j = 0; j < 4; ++j) {
          int col = n0 + wc + j * 16 + m16;
          float v = acc[i][j][r] + bias[col];
          if (RES == 1) v += ((const float*)res)[(size_t)row * N + col];
          if (RES == 2) v += b2f(((const unsigned short*)res)[(size_t)row * N + col]);
          if (GELU_ACT) v = 0.5f * v * (1.0f + erff(v * 0.70710678118654752f));
          if (OMODE == 1) outF[(size_t)row * N + col] = v;
          else            outB[(size_t)row * N + col] = f2b(v);
        }
      }
    }
  }
}

// ---------------------------------------------------------------------------
// Fused attention, S^T formulation, register-P, double-buffered staging.
// KVBLK=32 (R8): K tile [32][128], V tile [128][32], 32KB LDS total ->
// 4 blocks/CU. V is pre-permuted (key bit2<->3) so S^T C-layout registers
// ARE the PV A-operand fragments. No cross-lane exchange on QK->PV path.
// ---------------------------------------------------------------------------
__global__ __launch_bounds__(256, 4) void attn_kernel(const unsigned short* __restrict__ Qb_,
                                                      const unsigned short* __restrict__ Kb_,
                                                      int tstride,
                                                      const unsigned short* __restrict__ Vt,
                                                      unsigned short* __restrict__ CTX,
                                                      int pairs_per_xcd) {
  int xcd = blockIdx.x & 7;
  int i   = blockIdx.x >> 3;
  int pair = xcd * pairs_per_xcd + (i >> 3);
  int qt   = i & 7;
  int b = pair >> 2, h = pair & 3;
  int tid = threadIdx.x, lane = tid & 63, w = tid >> 6;
  int m32 = lane & 31, hf = lane >> 5;
  size_t qkoff = ((size_t)b * SEQ) * tstride + h * HDIM;
  const unsigned short* Qg = Qb_ + qkoff;
  const unsigned short* Kg = Kb_ + qkoff;
  const unsigned short* Vp = Vt + (size_t)pair * HDIM * SEQ;

  __shared__ unsigned short Klds[2][32 * 128];   // [key][hd], chunk-swizzled
  __shared__ unsigned short Vlds[2][128 * 32];   // [hd][slot], chunk-swizzled

  int qrow0 = qt * 128 + w * 32;
  bf16x8 qf[8];   // Q[q=qrow0+m32][hd=ks*16+hf*8+j]  (B-operand frags)
  {
    const unsigned short* qp = Qg + (size_t)(qrow0 + m32) * tstride + hf * 8;
#pragma unroll
    for (int ks = 0; ks < 8; ++ks) qf[ks] = *(const bf16x8*)(qp + ks * 16);
  }
  bf16x8 onesf;
#pragma unroll
  for (int j = 0; j < 8; ++j) onesf[j] = (short)0x3F80;  // bf16 1.0

  // staging source addresses (XOR-chunk swizzle folded into global address)
  // K: per wave rows 8w..8w+7; instr covers 4 rows; chunk ^= row&7 (16 chunks)
  const unsigned short* kpA = Kg + (size_t)(8 * w + (lane >> 4)) * tstride
                              + (((lane & 15) ^ (lane >> 4)) << 3);
  const unsigned short* kpB = Kg + (size_t)(8 * w + 4 + (lane >> 4)) * tstride
                              + (((lane & 15) ^ (4 + (lane >> 4))) << 3);
  // V: per wave rows 32w..32w+31 (hd); instr covers 16 rows of 64B;
  // chunk ^= (row>>1)&3 (4 chunks/row)
  const unsigned short* vpA = Vp + (size_t)(32 * w + (lane >> 2)) * SEQ
                              + (((lane & 3) ^ ((lane >> 3) & 3)) << 3);
  int klo = w * 1024;   // elems: 8 rows * 128
  int vlo = w * 1024;   // elems: 32 rows * 32

  // prologue: stage ktile 0 into buffer 0
  gl_lds16(kpA,            Klds[0] + klo);
  gl_lds16(kpB,            Klds[0] + klo + 512);
  gl_lds16(vpA,            Vlds[0] + vlo);
  gl_lds16(vpA + 16 * SEQ, Vlds[0] + vlo + 512);

  f32x16 o0 = {}, o1 = {}, o2 = {}, o3 = {};
  f32x16 lacc = {};

  for (int kt = 0; kt < 32; ++kt) {
    int cur = kt & 1, nxt = cur ^ 1;
    __syncthreads();   // buf[cur] ready; all waves done with buf[nxt]
    if (kt < 31) {     // stage ktile kt+1 into buf[nxt]
      kpA += 32 * tstride; kpB += 32 * tstride; vpA += 32;
      gl_lds16(kpA,            Klds[nxt] + klo);
      gl_lds16(kpB,            Klds[nxt] + klo + 512);
      gl_lds16(vpA,            Vlds[nxt] + vlo);
      gl_lds16(vpA + 16 * SEQ, Vlds[nxt] + vlo + 512);
    }
    const unsigned short* Kr = Klds[cur];
    const unsigned short* Vr = Vlds[cur];

    // S^T = K · Q^T : A = K-frags (m=key 32), B = Q-frags (registers)
    __builtin_amdgcn_s_setprio(1);
    f32x16 sc0 = {};
#pragma unroll
    for (int ks = 0; ks < 8; ++ks) {
      int ch = 2 * ks + hf;
      bf16x8 kf0 = *(const bf16x8*)(Kr + m32 * 128 + ((ch ^ (m32 & 7)) << 3));
      sc0 = __builtin_amdgcn_mfma_f32_32x32x16_bf16(kf0, qf[ks], sc0, 0, 0, 0);
    }
    __builtin_amdgcn_s_setprio(0);

    // P = exp2(S) (Q pre-scaled). With sigma-permuted V, the C-layout regs
    // are already A-frag order: pa[g] = pack(sc regs 8g..8g+7).
    bf16x8 pa[2];
#pragma unroll
    for (int g = 0; g < 2; ++g) {
      union { unsigned u[4]; bf16x8 v; } uu;
      uu.u[0] = pk2t(exp2f(sc0[8*g+0]), exp2f(sc0[8*g+1]));
      uu.u[1] = pk2t(exp2f(sc0[8*g+2]), exp2f(sc0[8*g+3]));
      uu.u[2] = pk2t(exp2f(sc0[8*g+4]), exp2f(sc0[8*g+5]));
      uu.u[3] = pk2t(exp2f(sc0[8*g+6]), exp2f(sc0[8*g+7]));
      pa[g] = uu.v;
    }

    // O += P · V ; l += P · ones  (lacc C-layout matches O C-layout)
    __builtin_amdgcn_s_setprio(1);
#pragma unroll
    for (int ks = 0; ks < 2; ++ks) {
      int ch = 2 * ks + hf;
      int vsw = (m32 >> 1) & 3;
      lacc = __builtin_amdgcn_mfma_f32_32x32x16_bf16(pa[ks], onesf, lacc, 0, 0, 0);
      {
        bf16x8 vf = *(const bf16x8*)(Vr + m32 * 32 + ((ch ^ vsw) << 3));
        o0 = __builtin_amdgcn_mfma_f32_32x32x16_bf16(pa[ks], vf, o0, 0, 0, 0);
      }
      {
        bf16x8 vf = *(const bf16x8*)(Vr + (32 + m32) * 32 + ((ch ^ vsw) << 3));
        o1 = __builtin_amdgcn_mfma_f32_32x32x16_bf16(pa[ks], vf, o1, 0, 0, 0);
      }
      {
        bf16x8 vf = *(const bf16x8*)(Vr + (64 + m32) * 32 + ((ch ^ vsw) << 3));
        o2 = __builtin_amdgcn_mfma_f32_32x32x16_bf16(pa[ks], vf, o2, 0, 0, 0);
      }
      {
        bf16x8 vf = *(const bf16x8*)(Vr + (96 + m32) * 32 + ((ch ^ vsw) << 3));
        o3 = __builtin_amdgcn_mfma_f32_32x32x16_bf16(pa[ks], vf, o3, 0, 0, 0);
      }
    }
    __builtin_amdgcn_s_setprio(0);
  }

  // store O normalized; lacc[reg] holds l for row (reg&3)+8*(reg>>2)+4*hf
  size_t obase = ((size_t)b * SEQ + qrow0) * DM + h * HDIM;
#pragma unroll
  for (int g = 0; g < 4; ++g) {
#pragma unroll
    for (int r = 0; r < 4; ++r) {
      int reg = 4 * g + r;
      int rowl = 8 * g + 4 * hf + r;
      float inv = 1.0f / lacc[reg];
      size_t off = obase + (size_t)rowl * DM + m32;
      CTX[off]      = f2b(o0[reg] * inv);
      CTX[off + 32] = f2b(o1[reg] * inv);
      CTX[off + 64] = f2b(o2[reg] * inv);
      CTX[off + 96] = f2b(o3[reg] * inv);
    }
  }
}

// ---------------------------------------------------------------------------
extern "C" void kernel_launch(void* const* d_in, const int* in_sizes, int n_in,
                              void* d_out, int out_size, void* d_ws, size_t ws_size,
                              hipStream_t stream) {
  const float* x1    = (const float*)d_in[0];
  const float* x2    = (const float*)d_in[1];
  const float* ln1_g = (const float*)d_in[2];
  const float* ln1_b = (const float*)d_in[3];
  const float* ln2_g = (const float*)d_in[4];
  const float* ln2_b = (const float*)d_in[5];
  const float* lnf_g = (const float*)d_in[6];
  const float* lnf_b = (const float*)d_in[7];
  P12 wsrc;
  for (int i = 0; i < 10; ++i) wsrc.p[i] = (const float*)d_in[8 + 2 * i];
  wsrc.p[10] = (const float*)d_in[28];   // W1
  wsrc.p[11] = (const float*)d_in[30];   // W2
  P9 bsrc;
  for (int i = 0; i < 9; ++i) bsrc.p[i] = (const float*)d_in[9 + 2 * i];
  const float* bo   = (const float*)d_in[27];
  const float* b1   = (const float*)d_in[29];
  const float* b2   = (const float*)d_in[31];

  char* ws = (char*)d_ws;
  size_t off = 0;
  auto alloc = [&](size_t bytes) -> char* {
    char* p = ws + off;
    off += (bytes + 255) & ~(size_t)255;
    return p;
  };
  unsigned short* WT0 = (unsigned short*)alloc((size_t)10 * 512 * 512 * 2);
  auto WT = [&](int i) { return WT0 + (size_t)i * 262144; };
  unsigned short* W1t = (unsigned short*)alloc((size_t)1024 * 512 * 2);
  unsigned short* W2t = (unsigned short*)alloc((size_t)512 * 1024 * 2);
  float*          bcc = (float*)alloc(4608 * 4);
  unsigned short* XN  = (unsigned short*)alloc((size_t)2 * MTOK * DM * 2);
  unsigned short* QKb = (unsigned short*)alloc((size_t)2 * MTOK * 1024 * 2);
  unsigned short* Vtb = (unsigned short*)alloc((size_t)128 * HDIM * SEQ * 2);
  unsigned short* CT  = (unsigned short*)alloc((size_t)2 * MTOK * DM * 2);
  float*          Xf  = (float*)alloc((size_t)MTOK * DM * 4);
  unsigned short* XN1 = XN + (size_t)MTOK * DM;
  unsigned short* MID = QKb;                       // alias (Q12/K12 dead)
  unsigned short* HN  = Vtb;                       // alias (Vt dead)
  float* bias_self  = bcc;                         // [2][1536]
  float* bias_cross = bcc + 3072;                  // [1536]

  // 0) prep: 12 weight transposes + bias concat, one dispatch
  prep_kernel<<<3602, 256, 0, stream>>>(wsrc, bsrc, WT0, W1t, W2t, bcc);

  // 1) both LayerNorms
  ln_kernel<<<2 * MTOK / 4, 256, 0, stream>>>(x1, x2, ln1_g, ln1_b, ln2_g, ln2_b, XN, XN1);

  // 2) self QKV, both streams, one dispatch: M=32768, N=1536 (Q pre-scaled)
  gemm_kernel<0, false, 3><<<3072, 256, 0, stream>>>(XN, nullptr, WT0, bias_self,
      nullptr, nullptr, QKb, Vtb, 32768, 1536, 512);

  // 3) self-attention, both streams: 128 pairs
  attn_kernel<<<128 * 8, 256, 0, stream>>>(QKb, QKb + 512, 1024, Vtb, CT, 16);

  // 4) out-proj + bias + residual(xn) -> src (in-place over XN, bf16)
  gemm_kernel<2, false, 0><<<1024, 256, 0, stream>>>(CT, nullptr, WT(9), bo, XN,
      nullptr, XN, nullptr, 32768, 512, 512);

  // 5) cross QKV, one dispatch: Q from src1(XN), K/V from src2(XN1)
  gemm_kernel<0, false, 4><<<1536, 256, 0, stream>>>(XN, XN1, WT(6), bias_cross,
      nullptr, nullptr, QKb, Vtb, 16384, 1536, 512);

  // 6) cross-attention: 64 pairs
  attn_kernel<<<64 * 8, 256, 0, stream>>>(QKb, QKb + (size_t)MTOK * 512, 512, Vtb, CT, 8);

  // 7) out-proj + bias + residual(identity x1, fp32) -> x (fp32)
  gemm_kernel<1, false, 1><<<512, 256, 0, stream>>>(CT, nullptr, WT(9), bo, x1,
      Xf, nullptr, nullptr, 16384, 512, 512);

  // 8) final LN
  ln_kernel<<<MTOK / 4, 256, 0, stream>>>(Xf, Xf, lnf_g, lnf_b, lnf_g, lnf_b, HN, HN);

  // 9) MLP: gelu(h@W1+b1) -> MID ; MID@W2+b2 + x -> out (fp32)
  gemm_kernel<0, true,  0><<<1024, 256, 0, stream>>>(HN, nullptr, W1t, b1,
      nullptr, nullptr, MID, nullptr, 16384, 1024, 512);
  gemm_kernel<1, false, 1><<<512, 256, 0, stream>>>(MID, nullptr, W2t, b2,
      Xf, (float*)d_out, nullptr, nullptr, 16384, 512, 1024);
}

// Round 3
// 535.703 us; speedup vs baseline: 1.3268x; 1.3268x over previous
//
#include <hip/hip_runtime.h>
#include <math.h>

// ---------------------------------------------------------------------------
// Block_42167988912800: dual-stream transformer block on gfx950.
// B=16 S=1024 D=512 H=4 hd=128 MLP=1024, fp32 in/out, bf16 MFMA compute.
// R6: XCD-affine GEMM grid mapping.
// R7: GEMM XOR-chunk LDS swizzle + double-buffered staging.
// R8: FAILED (reverted): attn KVBLK=32 @ 4 blocks/CU blew the per-XCD L2
//     pair budget (16 pairs x 512KB = 8MB > 4MB) -> FETCH 49->574MB, HBM-
//     bound. Attn occupancy is L2-capacity-capped at 2 blocks/CU.
// R9: attn back to R7 structure (+ s_setprio around MFMA, T5).
//     GEMM: BK 64->32, LDS 32KB -> 4 blocks/CU (GEMM working set is small,
//     occupancy lever IS available there). GEMM was latency-bound: neither
//     LDS (~1260 TF ceiling) nor MFMA (~2000 TF) saturated at ~500 TF; the
//     per-K-step vmcnt(0) drain dominates -> overlap across 4 blocks.
// ---------------------------------------------------------------------------

#define SEQ   1024
#define DM    512
#define HDIM  128
#define MTOK  16384
#define MLPD  1024
#define SC2   ((float)(0.08838834764831845 * 1.4426950408889634))  // scale*log2e

typedef short bf16x8 __attribute__((ext_vector_type(8)));
typedef float f32x4  __attribute__((ext_vector_type(4)));
typedef float f32x16 __attribute__((ext_vector_type(16)));
typedef unsigned short us4 __attribute__((ext_vector_type(4)));

typedef unsigned int u32g __attribute__((address_space(1)));
typedef unsigned int u32l __attribute__((address_space(3)));

static __device__ __forceinline__ unsigned short f2b(float f) {
  union { float f; unsigned u; } v; v.f = f;
  unsigned r = v.u + 0x7FFFu + ((v.u >> 16) & 1u);
  return (unsigned short)(r >> 16);
}
static __device__ __forceinline__ float b2f(unsigned short h) {
  union { unsigned u; float f; } v; v.u = ((unsigned)h) << 16;
  return v.f;
}
// truncating pack: two floats -> two bf16 in one u32 [lo=a, hi=b]
static __device__ __forceinline__ unsigned pk2t(float a, float b) {
  union { float f; unsigned u; } va, vb; va.f = a; vb.f = b;
  return __builtin_amdgcn_perm(vb.u, va.u, 0x07060302u);
}
static __device__ __forceinline__ void gl_lds16(const void* g, void* l) {
  __builtin_amdgcn_global_load_lds((u32g*)g, (u32l*)l, 16, 0, 0);
}

// ---------------------------------------------------------------------------
// Prep: 12 weight transposes (fp32 [K][N] -> bf16 [N][K]) + 9-bias concat.
// ---------------------------------------------------------------------------
struct P12 { const float* p[12]; };
struct P9  { const float* p[9]; };

__global__ __launch_bounds__(256) void prep_kernel(P12 ws, P9 bs,
                                                   unsigned short* __restrict__ WT0,
                                                   unsigned short* __restrict__ W1t,
                                                   unsigned short* __restrict__ W2t,
                                                   float* __restrict__ bcc) {
  int bid = blockIdx.x;
  if (bid >= 3584) {
    int i = (bid - 3584) * 256 + threadIdx.x;
    if (i < 4608) bcc[i] = bs.p[i >> 9][i & 511];
    return;
  }
  __shared__ float t[32][33];
  const float* W; unsigned short* Wt; int K, N, tt;
  if (bid < 2560)      { int wi = bid >> 8; W = ws.p[wi]; Wt = WT0 + (size_t)wi * 262144; K = 512; N = 512; tt = bid & 255; }
  else if (bid < 3072) { W = ws.p[10]; Wt = W1t; K = 512;  N = 1024; tt = bid - 2560; }
  else                 { W = ws.p[11]; Wt = W2t; K = 1024; N = 512;  tt = bid - 3072; }
  int ntiles = N >> 5;
  int bx = tt % ntiles, by = tt / ntiles;
  int n0 = bx * 32, k0 = by * 32;
  int tx = threadIdx.x & 31, ty = threadIdx.x >> 5;
#pragma unroll
  for (int i = 0; i < 32; i += 8)
    t[ty + i][tx] = W[(size_t)(k0 + ty + i) * N + n0 + tx];
  __syncthreads();
#pragma unroll
  for (int i = 0; i < 32; i += 8)
    Wt[(size_t)(n0 + ty + i) * K + k0 + tx] = f2b(t[tx][ty + i]);
}

// ---------------------------------------------------------------------------
// Dual LayerNorm: one wave per row of 512, writes bf16.
// ---------------------------------------------------------------------------
__global__ __launch_bounds__(256) void ln_kernel(const float* __restrict__ X0,
                                                 const float* __restrict__ X1,
                                                 const float* __restrict__ g0w,
                                                 const float* __restrict__ b0w,
                                                 const float* __restrict__ g1w,
                                                 const float* __restrict__ b1w,
                                                 unsigned short* __restrict__ out0,
                                                 unsigned short* __restrict__ out1) {
  int idx  = blockIdx.x * 4 + (threadIdx.x >> 6);
  int sel  = idx >> 14;
  int row  = idx & 16383;
  const float* X = sel ? X1 : X0;
  const float* gw = sel ? g1w : g0w;
  const float* bw = sel ? b1w : b0w;
  unsigned short* outB = sel ? out1 : out0;
  int lane = threadIdx.x & 63;
  const float4* xr = (const float4*)(X + (size_t)row * DM);
  float4 a = xr[lane];
  float4 c = xr[lane + 64];
  float s  = a.x + a.y + a.z + a.w + c.x + c.y + c.z + c.w;
  float s2 = a.x*a.x + a.y*a.y + a.z*a.z + a.w*a.w
           + c.x*c.x + c.y*c.y + c.z*c.z + c.w*c.w;
#pragma unroll
  for (int off = 1; off < 64; off <<= 1) {
    s  += __shfl_xor(s,  off, 64);
    s2 += __shfl_xor(s2, off, 64);
  }
  float mean = s * (1.0f / 512.0f);
  float var  = s2 * (1.0f / 512.0f) - mean * mean;
  float rstd = rsqrtf(var + 1e-6f);
  const float4* gv = (const float4*)gw;
  const float4* bv = (const float4*)bw;
  float4 g1 = gv[lane], g2 = gv[lane + 64];
  float4 b1 = bv[lane], b2 = bv[lane + 64];
  us4 o1, o2;
  o1.x = f2b((a.x - mean) * rstd * g1.x + b1.x);
  o1.y = f2b((a.y - mean) * rstd * g1.y + b1.y);
  o1.z = f2b((a.z - mean) * rstd * g1.z + b1.z);
  o1.w = f2b((a.w - mean) * rstd * g1.w + b1.w);
  o2.x = f2b((c.x - mean) * rstd * g2.x + b2.x);
  o2.y = f2b((c.y - mean) * rstd * g2.y + b2.y);
  o2.z = f2b((c.z - mean) * rstd * g2.z + b2.z);
  o2.w = f2b((c.w - mean) * rstd * g2.w + b2.w);
  *(us4*)(outB + (size_t)row * DM + lane * 4)        = o1;
  *(us4*)(outB + (size_t)row * DM + (lane + 64) * 4) = o2;
}

// ---------------------------------------------------------------------------
// bf16 MFMA GEMM: C[M,N] = A[M,K] @ Bt[N,K]^T + bias (+res)(gelu)
// XCD-affine grid; BK=32, double-buffered LDS (32KB) -> 4 blocks/CU.
// Chunk swizzle (4 chunks of 16B per row): chunk ^= (row ^ row>>2)&3,
// folded into global source address; reads apply the same XOR.
// RES: 0 none, 1 fp32 residual, 2 bf16 residual.
// OMODE 0: bf16 out. 1: fp32 out. 3: self-QKV. 4: cross-QKV.
// ---------------------------------------------------------------------------
template <int RES, bool GELU_ACT, int OMODE>
__global__ __launch_bounds__(256, 4) void gemm_kernel(const unsigned short* __restrict__ A,
                                                      const unsigned short* __restrict__ A1,
                                                      const unsigned short* __restrict__ Bt,
                                                      const float* __restrict__ bias,
                                                      const void* __restrict__ res,
                                                      float* __restrict__ outF,
                                                      unsigned short* __restrict__ outB,
                                                      unsigned short* __restrict__ outV,
                                                      int M, int N, int K) {
  int nT = N >> 7;
  int mT = M >> 7;
  int xcd = blockIdx.x & 7;
  int idx = blockIdx.x >> 3;
  int mPerX = mT >> 3;
  int q = idx / nT;
  int tm = xcd * mPerX + q;
  int tn = idx - q * nT;
  int m0 = tm << 7, n0 = tn << 7;
  int tid = threadIdx.x, lane = tid & 63, w = tid >> 6;
  int m16 = lane & 15, q4 = lane >> 4;
  int wr = (w & 1) << 6, wc = (w >> 1) << 6;
  __shared__ unsigned short Alds[2][128 * 32];
  __shared__ unsigned short Blds[2][128 * 32];
  f32x4 acc[4][4] = {};

  const unsigned short* Aeff = A;
  const unsigned short* Bteff = Bt;
  const float* biaseff = bias;
  if (OMODE == 3) {
    int half = tm >> 7;
    Bteff = Bt + (size_t)half * 3 * 262144;
    biaseff = bias + half * 1536;
  }
  if (OMODE == 4) {
    if (tn >= 4) Aeff = A1;
  }

  // staging: per it (0..1), lane owns row = it*64 + w*16 + (lane>>2),
  // LDS chunk lane&3. Swizzle folded into global col: chunk ^= (r^(r>>2))&3.
  // For this geometry swz = ((lane>>2) ^ (lane>>4)) & 3 (w/it-independent).
  int swz  = ((lane >> 2) ^ (lane >> 4)) & 3;
  int scol = ((lane & 3) ^ swz) << 3;
  const unsigned short* Ag = Aeff  + (size_t)(m0 + w * 16 + (lane >> 2)) * K + scol;
  const unsigned short* Bg = Bteff + (size_t)(n0 + w * 16 + (lane >> 2)) * K + scol;
  int ldst = w * 512;   // elems: 16 rows * 32

#pragma unroll
  for (int it = 0; it < 2; ++it) {
    gl_lds16(Ag + (size_t)it * 64 * K, Alds[0] + it * 2048 + ldst);
    gl_lds16(Bg + (size_t)it * 64 * K, Blds[0] + it * 2048 + ldst);
  }

  // read-side swizzle: row = wr+i*16+m16 -> (row^(row>>2))&3 = (m16^(m16>>2))&3
  int rsw  = (m16 ^ (m16 >> 2)) & 3;
  int roff = (q4 ^ rsw) << 3;

  int nk = K >> 5;
  for (int ks = 0; ks < nk; ++ks) {
    int cur = ks & 1, nxt = cur ^ 1;
    __syncthreads();
    if (ks + 1 < nk) {
      int k0n = (ks + 1) << 5;
#pragma unroll
      for (int it = 0; it < 2; ++it) {
        gl_lds16(Ag + (size_t)it * 64 * K + k0n, Alds[nxt] + it * 2048 + ldst);
        gl_lds16(Bg + (size_t)it * 64 * K + k0n, Blds[nxt] + it * 2048 + ldst);
      }
    }
    const unsigned short* Ar = Alds[cur];
    const unsigned short* Br = Blds[cur];
    bf16x8 af[4], bfr[4];
#pragma unroll
    for (int i = 0; i < 4; ++i)
      af[i] = *(const bf16x8*)(Ar + (wr + i * 16 + m16) * 32 + roff);
#pragma unroll
    for (int j = 0; j < 4; ++j)
      bfr[j] = *(const bf16x8*)(Br + (wc + j * 16 + m16) * 32 + roff);
#pragma unroll
    for (int i = 0; i < 4; ++i)
#pragma unroll
      for (int j = 0; j < 4; ++j)
        acc[i][j] = __builtin_amdgcn_mfma_f32_16x16x32_bf16(af[i], bfr[j], acc[i][j], 0, 0, 0);
  }
  // epilogue: C/D layout col=lane&15, row=(lane>>4)*4+reg
  if (OMODE == 3 || OMODE == 4) {
    if (n0 < 1024) {
      int stride = (OMODE == 3) ? 1024 : 512;
      unsigned short* ob = outB;
      int coff = 0;
      if (OMODE == 4 && n0 >= 512) { ob = outB + (size_t)MTOK * 512; coff = 512; }
      float sc = (n0 < 512) ? SC2 : 1.0f;     // fold softmax scale into Q
#pragma unroll
      for (int i = 0; i < 4; ++i) {
#pragma unroll
        for (int r = 0; r < 4; ++r) {
          int row = m0 + wr + i * 16 + q4 * 4 + r;
#pragma unroll
          for (int j = 0; j < 4; ++j) {
            int col = n0 + wc + j * 16 + m16;
            ob[(size_t)row * stride + col - coff] = f2b((acc[i][j][r] + biaseff[col]) * sc);
          }
        }
      }
    } else {
#pragma unroll
      for (int i = 0; i < 4; ++i) {
        int row0 = m0 + wr + i * 16 + q4 * 4;
        int s = row0 & 1023, bl = row0 >> 10;
        // key-permutation sigma: swap bit2 <-> bit3 of seq index (4-aligned
        // groups keep their us4 contiguity). PV contracts over this order.
        s = (s & ~12) | ((s & 4) << 1) | ((s & 8) >> 1);
#pragma unroll
        for (int j = 0; j < 4; ++j) {
          int col = n0 + wc + j * 16 + m16;
          int hh = (col - 1024) >> 7, hd = col & 127;
          float bb = biaseff[col];
          us4 pkv;
          pkv.x = f2b(acc[i][j][0] + bb);
          pkv.y = f2b(acc[i][j][1] + bb);
          pkv.z = f2b(acc[i][j][2] + bb);
          pkv.w = f2b(acc[i][j][3] + bb);
          *(us4*)(outV + (((size_t)(bl * 4 + hh)) * HDIM + hd) * SEQ + s) = pkv;
        }
      }
    }
  } else {
#pragma unroll
    for (int i = 0; i < 4; ++i) {
#pragma unroll
      for (int r = 0; r < 4; ++r) {
        int row = m0 + wr + i * 16 + q4 * 4 + r;
#pragma unroll
        for (int j = 0; j < 4; ++j) {
          int col = n0 + wc + j * 16 + m16;
          float v = acc[i][j][r] + bias[col];
          if (RES == 1) v += ((const float*)res)[(size_t)row * N + col];
          if (RES == 2) v += b2f(((const unsigned short*)res)[(size_t)row * N + col]);
          if (GELU_ACT) v = 0.5f * v * (1.0f + erff(v * 0.70710678118654752f));
          if (OMODE == 1) outF[(size_t)row * N + col] = v;
          else            outB[(size_t)row * N + col] = f2b(v);
        }
      }
    }
  }
}

// ---------------------------------------------------------------------------
// Fused attention, S^T formulation, register-P, double-buffered staging.
// R7 structure: KVBLK=64, 64KB LDS, 2 blocks/CU (L2 pair budget: 8 pairs
// x 512KB = 4MB per XCD -- do NOT raise occupancy here, see R8 note).
// V is pre-permuted (key bit2<->3) so the S^T C-layout registers ARE the
// PV A-operand fragments. No cross-lane exchange on the QK->PV path.
// ---------------------------------------------------------------------------
__global__ __launch_bounds__(256, 2) void attn_kernel(const unsigned short* __restrict__ Qb_,
                                                      const unsigned short* __restrict__ Kb_,
                                                      int tstride,
                                                      const unsigned short* __restrict__ Vt,
                                                      unsigned short* __restrict__ CTX,
                                                      int pairs_per_xcd) {
  int xcd = blockIdx.x & 7;
  int i   = blockIdx.x >> 3;
  int pair = xcd * pairs_per_xcd + (i >> 3);
  int qt   = i & 7;
  int b = pair >> 2, h = pair & 3;
  int tid = threadIdx.x, lane = tid & 63, w = tid >> 6;
  int m32 = lane & 31, hf = lane >> 5;
  size_t qkoff = ((size_t)b * SEQ) * tstride + h * HDIM;
  const unsigned short* Qg = Qb_ + qkoff;
  const unsigned short* Kg = Kb_ + qkoff;
  const unsigned short* Vp = Vt + (size_t)pair * HDIM * SEQ;

  __shared__ unsigned short Klds[2][64 * 128];   // [key][hd], chunk-swizzled
  __shared__ unsigned short Vlds[2][128 * 64];   // [hd][slot], chunk-swizzled

  int qrow0 = qt * 128 + w * 32;
  bf16x8 qf[8];   // Q[q=qrow0+m32][hd=ks*16+hf*8+j]  (B-operand frags)
  {
    const unsigned short* qp = Qg + (size_t)(qrow0 + m32) * tstride + hf * 8;
#pragma unroll
    for (int ks = 0; ks < 8; ++ks) qf[ks] = *(const bf16x8*)(qp + ks * 16);
  }
  bf16x8 onesf;
#pragma unroll
  for (int j = 0; j < 8; ++j) onesf[j] = (short)0x3F80;  // bf16 1.0

  // staging source addresses (XOR-chunk swizzle folded into global address)
  const unsigned short* kp0 = Kg + (size_t)(16 * w + (lane >> 4)) * tstride
                              + (((lane & 15) ^ (lane >> 4)) << 3);
  const unsigned short* kp1 = Kg + (size_t)(16 * w + 4 + (lane >> 4)) * tstride
                              + (((lane & 15) ^ ((lane >> 4) + 4)) << 3);
  const unsigned short* vp0 = Vp + (size_t)(32 * w + (lane >> 3)) * SEQ
                              + (((lane & 7) ^ (lane >> 3)) << 3);
  int klo = 16 * w * 128;
  int vlo = 32 * w * 64;

  // prologue: stage ktile 0 into buffer 0
  gl_lds16(kp0,               Klds[0] + klo);
  gl_lds16(kp1,               Klds[0] + klo + 4 * 128);
  gl_lds16(kp0 + 8 * tstride, Klds[0] + klo + 8 * 128);
  gl_lds16(kp1 + 8 * tstride, Klds[0] + klo + 12 * 128);
  gl_lds16(vp0,               Vlds[0] + vlo);
  gl_lds16(vp0 + 8 * SEQ,     Vlds[0] + vlo + 8 * 64);
  gl_lds16(vp0 + 16 * SEQ,    Vlds[0] + vlo + 16 * 64);
  gl_lds16(vp0 + 24 * SEQ,    Vlds[0] + vlo + 24 * 64);

  f32x16 o0 = {}, o1 = {}, o2 = {}, o3 = {};
  f32x16 lacc = {};

  for (int kt = 0; kt < 16; ++kt) {
    int cur = kt & 1, nxt = cur ^ 1;
    __syncthreads();   // buf[cur] ready; all waves done with buf[nxt]
    if (kt < 15) {     // stage ktile kt+1 into buf[nxt]
      kp0 += 64 * tstride; kp1 += 64 * tstride; vp0 += 64;
      gl_lds16(kp0,               Klds[nxt] + klo);
      gl_lds16(kp1,               Klds[nxt] + klo + 4 * 128);
      gl_lds16(kp0 + 8 * tstride, Klds[nxt] + klo + 8 * 128);
      gl_lds16(kp1 + 8 * tstride, Klds[nxt] + klo + 12 * 128);
      gl_lds16(vp0,               Vlds[nxt] + vlo);
      gl_lds16(vp0 + 8 * SEQ,     Vlds[nxt] + vlo + 8 * 64);
      gl_lds16(vp0 + 16 * SEQ,    Vlds[nxt] + vlo + 16 * 64);
      gl_lds16(vp0 + 24 * SEQ,    Vlds[nxt] + vlo + 24 * 64);
    }
    const unsigned short* Kr = Klds[cur];
    const unsigned short* Vr = Vlds[cur];

    // S^T = K · Q^T : A = K-frags (m=key), B = Q-frags (registers)
    __builtin_amdgcn_s_setprio(1);
    f32x16 sc0 = {}, sc1 = {};
#pragma unroll
    for (int ks = 0; ks < 8; ++ks) {
      int ch = 2 * ks + hf;
      bf16x8 kf0 = *(const bf16x8*)(Kr + m32 * 128 + ((ch ^ (m32 & 7)) << 3));
      sc0 = __builtin_amdgcn_mfma_f32_32x32x16_bf16(kf0, qf[ks], sc0, 0, 0, 0);
      int k1r = 32 + m32;
      bf16x8 kf1 = *(const bf16x8*)(Kr + k1r * 128 + ((ch ^ (k1r & 7)) << 3));
      sc1 = __builtin_amdgcn_mfma_f32_32x32x16_bf16(kf1, qf[ks], sc1, 0, 0, 0);
    }
    __builtin_amdgcn_s_setprio(0);

    // P = exp2(S) (Q pre-scaled). With sigma-permuted V, the C-layout regs
    // are already A-frag order: pa[ks] = pack(sc regs 8ks..8ks+7).
    bf16x8 pa[4];
#pragma unroll
    for (int t = 0; t < 2; ++t) {
      const f32x16& sc = t ? sc1 : sc0;
#pragma unroll
      for (int g = 0; g < 2; ++g) {
        union { unsigned u[4]; bf16x8 v; } uu;
        uu.u[0] = pk2t(exp2f(sc[8*g+0]), exp2f(sc[8*g+1]));
        uu.u[1] = pk2t(exp2f(sc[8*g+2]), exp2f(sc[8*g+3]));
        uu.u[2] = pk2t(exp2f(sc[8*g+4]), exp2f(sc[8*g+5]));
        uu.u[3] = pk2t(exp2f(sc[8*g+6]), exp2f(sc[8*g+7]));
        pa[2*t + g] = uu.v;
      }
    }

    // O += P · V ; l += P · ones  (lacc C-layout matches O C-layout)
    __builtin_amdgcn_s_setprio(1);
#pragma unroll
    for (int ks = 0; ks < 4; ++ks) {
      int ch = 2 * ks + hf;
      int sw = m32 & 7;
      lacc = __builtin_amdgcn_mfma_f32_32x32x16_bf16(pa[ks], onesf, lacc, 0, 0, 0);
      {
        bf16x8 vf = *(const bf16x8*)(Vr + m32 * 64 + ((ch ^ sw) << 3));
        o0 = __builtin_amdgcn_mfma_f32_32x32x16_bf16(pa[ks], vf, o0, 0, 0, 0);
      }
      {
        bf16x8 vf = *(const bf16x8*)(Vr + (32 + m32) * 64 + ((ch ^ sw) << 3));
        o1 = __builtin_amdgcn_mfma_f32_32x32x16_bf16(pa[ks], vf, o1, 0, 0, 0);
      }
      {
        bf16x8 vf = *(const bf16x8*)(Vr + (64 + m32) * 64 + ((ch ^ sw) << 3));
        o2 = __builtin_amdgcn_mfma_f32_32x32x16_bf16(pa[ks], vf, o2, 0, 0, 0);
      }
      {
        bf16x8 vf = *(const bf16x8*)(Vr + (96 + m32) * 64 + ((ch ^ sw) << 3));
        o3 = __builtin_amdgcn_mfma_f32_32x32x16_bf16(pa[ks], vf, o3, 0, 0, 0);
      }
    }
    __builtin_amdgcn_s_setprio(0);
  }

  // store O normalized; lacc[reg] holds l for row (reg&3)+8*(reg>>2)+4*hf
  size_t obase = ((size_t)b * SEQ + qrow0) * DM + h * HDIM;
#pragma unroll
  for (int g = 0; g < 4; ++g) {
#pragma unroll
    for (int r = 0; r < 4; ++r) {
      int reg = 4 * g + r;
      int rowl = 8 * g + 4 * hf + r;
      float inv = 1.0f / lacc[reg];
      size_t off = obase + (size_t)rowl * DM + m32;
      CTX[off]      = f2b(o0[reg] * inv);
      CTX[off + 32] = f2b(o1[reg] * inv);
      CTX[off + 64] = f2b(o2[reg] * inv);
      CTX[off + 96] = f2b(o3[reg] * inv);
    }
  }
}

// ---------------------------------------------------------------------------
extern "C" void kernel_launch(void* const* d_in, const int* in_sizes, int n_in,
                              void* d_out, int out_size, void* d_ws, size_t ws_size,
                              hipStream_t stream) {
  const float* x1    = (const float*)d_in[0];
  const float* x2    = (const float*)d_in[1];
  const float* ln1_g = (const float*)d_in[2];
  const float* ln1_b = (const float*)d_in[3];
  const float* ln2_g = (const float*)d_in[4];
  const float* ln2_b = (const float*)d_in[5];
  const float* lnf_g = (const float*)d_in[6];
  const float* lnf_b = (const float*)d_in[7];
  P12 wsrc;
  for (int i = 0; i < 10; ++i) wsrc.p[i] = (const float*)d_in[8 + 2 * i];
  wsrc.p[10] = (const float*)d_in[28];   // W1
  wsrc.p[11] = (const float*)d_in[30];   // W2
  P9 bsrc;
  for (int i = 0; i < 9; ++i) bsrc.p[i] = (const float*)d_in[9 + 2 * i];
  const float* bo   = (const float*)d_in[27];
  const float* b1   = (const float*)d_in[29];
  const float* b2   = (const float*)d_in[31];

  char* ws = (char*)d_ws;
  size_t off = 0;
  auto alloc = [&](size_t bytes) -> char* {
    char* p = ws + off;
    off += (bytes + 255) & ~(size_t)255;
    return p;
  };
  unsigned short* WT0 = (unsigned short*)alloc((size_t)10 * 512 * 512 * 2);
  auto WT = [&](int i) { return WT0 + (size_t)i * 262144; };
  unsigned short* W1t = (unsigned short*)alloc((size_t)1024 * 512 * 2);
  unsigned short* W2t = (unsigned short*)alloc((size_t)512 * 1024 * 2);
  float*          bcc = (float*)alloc(4608 * 4);
  unsigned short* XN  = (unsigned short*)alloc((size_t)2 * MTOK * DM * 2);
  unsigned short* QKb = (unsigned short*)alloc((size_t)2 * MTOK * 1024 * 2);
  unsigned short* Vtb = (unsigned short*)alloc((size_t)128 * HDIM * SEQ * 2);
  unsigned short* CT  = (unsigned short*)alloc((size_t)2 * MTOK * DM * 2);
  float*          Xf  = (float*)alloc((size_t)MTOK * DM * 4);
  unsigned short* XN1 = XN + (size_t)MTOK * DM;
  unsigned short* MID = QKb;                       // alias (Q12/K12 dead)
  unsigned short* HN  = Vtb;                       // alias (Vt dead)
  float* bias_self  = bcc;                         // [2][1536]
  float* bias_cross = bcc + 3072;                  // [1536]

  // 0) prep: 12 weight transposes + bias concat, one dispatch
  prep_kernel<<<3602, 256, 0, stream>>>(wsrc, bsrc, WT0, W1t, W2t, bcc);

  // 1) both LayerNorms
  ln_kernel<<<2 * MTOK / 4, 256, 0, stream>>>(x1, x2, ln1_g, ln1_b, ln2_g, ln2_b, XN, XN1);

  // 2) self QKV, both streams, one dispatch: M=32768, N=1536 (Q pre-scaled)
  gemm_kernel<0, false, 3><<<3072, 256, 0, stream>>>(XN, nullptr, WT0, bias_self,
      nullptr, nullptr, QKb, Vtb, 32768, 1536, 512);

  // 3) self-attention, both streams: 128 pairs
  attn_kernel<<<128 * 8, 256, 0, stream>>>(QKb, QKb + 512, 1024, Vtb, CT, 16);

  // 4) out-proj + bias + residual(xn) -> src (in-place over XN, bf16)
  gemm_kernel<2, false, 0><<<1024, 256, 0, stream>>>(CT, nullptr, WT(9), bo, XN,
      nullptr, XN, nullptr, 32768, 512, 512);

  // 5) cross QKV, one dispatch: Q from src1(XN), K/V from src2(XN1)
  gemm_kernel<0, false, 4><<<1536, 256, 0, stream>>>(XN, XN1, WT(6), bias_cross,
      nullptr, nullptr, QKb, Vtb, 16384, 1536, 512);

  // 6) cross-attention: 64 pairs
  attn_kernel<<<64 * 8, 256, 0, stream>>>(QKb, QKb + (size_t)MTOK * 512, 512, Vtb, CT, 8);

  // 7) out-proj + bias + residual(identity x1, fp32) -> x (fp32)
  gemm_kernel<1, false, 1><<<512, 256, 0, stream>>>(CT, nullptr, WT(9), bo, x1,
      Xf, nullptr, nullptr, 16384, 512, 512);

  // 8) final LN
  ln_kernel<<<MTOK / 4, 256, 0, stream>>>(Xf, Xf, lnf_g, lnf_b, lnf_g, lnf_b, HN, HN);

  // 9) MLP: gelu(h@W1+b1) -> MID ; MID@W2+b2 + x -> out (fp32)
  gemm_kernel<0, true,  0><<<1024, 256, 0, stream>>>(HN, nullptr, W1t, b1,
      nullptr, nullptr, MID, nullptr, 16384, 1024, 512);
  gemm_kernel<1, false, 1><<<512, 256, 0, stream>>>(MID, nullptr, W2t, b2,
      Xf, (float*)d_out, nullptr, nullptr, 16384, 512, 1024);
}

// Round 4
// 515.070 us; speedup vs baseline: 1.3800x; 1.0401x over previous
//
#include <hip/hip_runtime.h>
#include <math.h>

// ---------------------------------------------------------------------------
// Block_42167988912800: dual-stream transformer block on gfx950.
// B=16 S=1024 D=512 H=4 hd=128 MLP=1024, fp32 in/out, bf16 MFMA compute.
// R6: XCD-affine GEMM grid mapping.
// R7: GEMM XOR-chunk LDS swizzle + double-buffered staging (BK=64, 2 blk/CU).
// R8: FAILED: attn KVBLK=32 @ 4 blk/CU blew per-XCD L2 pair budget -> HBM-bound.
// R9: FAILED both: attn setprio -5us (lockstep waves, no role split);
//     GEMM BK=32 -8us (extra barriers > occupancy gain). Both reverted.
// R10: attn exp2f -> raw v_exp_f32 (inline asm). Default exp2f lowers to the
//     OCML guarded sequence (~6 VALU instr); 32 calls sit serially between
//     QK and PV each kt = ~the entire 40% VALUBusy. Raw v_exp is 1 instr
//     (scores pre-scaled by log2e, |S| << 126 so guards are dead weight).
// ---------------------------------------------------------------------------

#define SEQ   1024
#define DM    512
#define HDIM  128
#define MTOK  16384
#define MLPD  1024
#define SC2   ((float)(0.08838834764831845 * 1.4426950408889634))  // scale*log2e

typedef short bf16x8 __attribute__((ext_vector_type(8)));
typedef float f32x4  __attribute__((ext_vector_type(4)));
typedef float f32x16 __attribute__((ext_vector_type(16)));
typedef unsigned short us4 __attribute__((ext_vector_type(4)));

typedef unsigned int u32g __attribute__((address_space(1)));
typedef unsigned int u32l __attribute__((address_space(3)));

static __device__ __forceinline__ unsigned short f2b(float f) {
  union { float f; unsigned u; } v; v.f = f;
  unsigned r = v.u + 0x7FFFu + ((v.u >> 16) & 1u);
  return (unsigned short)(r >> 16);
}
static __device__ __forceinline__ float b2f(unsigned short h) {
  union { unsigned u; float f; } v; v.u = ((unsigned)h) << 16;
  return v.f;
}
// truncating pack: two floats -> two bf16 in one u32 [lo=a, hi=b]
static __device__ __forceinline__ unsigned pk2t(float a, float b) {
  union { float f; unsigned u; } va, vb; va.f = a; vb.f = b;
  return __builtin_amdgcn_perm(vb.u, va.u, 0x07060302u);
}
// raw 2^x: v_exp_f32, no libm guard sequence (inputs bounded, pre-scaled)
static __device__ __forceinline__ float ex2(float x) {
  float r; asm("v_exp_f32 %0, %1" : "=v"(r) : "v"(x)); return r;
}
static __device__ __forceinline__ void gl_lds16(const void* g, void* l) {
  __builtin_amdgcn_global_load_lds((u32g*)g, (u32l*)l, 16, 0, 0);
}

// ---------------------------------------------------------------------------
// Prep: 12 weight transposes (fp32 [K][N] -> bf16 [N][K]) + 9-bias concat.
// ---------------------------------------------------------------------------
struct P12 { const float* p[12]; };
struct P9  { const float* p[9]; };

__global__ __launch_bounds__(256) void prep_kernel(P12 ws, P9 bs,
                                                   unsigned short* __restrict__ WT0,
                                                   unsigned short* __restrict__ W1t,
                                                   unsigned short* __restrict__ W2t,
                                                   float* __restrict__ bcc) {
  int bid = blockIdx.x;
  if (bid >= 3584) {
    int i = (bid - 3584) * 256 + threadIdx.x;
    if (i < 4608) bcc[i] = bs.p[i >> 9][i & 511];
    return;
  }
  __shared__ float t[32][33];
  const float* W; unsigned short* Wt; int K, N, tt;
  if (bid < 2560)      { int wi = bid >> 8; W = ws.p[wi]; Wt = WT0 + (size_t)wi * 262144; K = 512; N = 512; tt = bid & 255; }
  else if (bid < 3072) { W = ws.p[10]; Wt = W1t; K = 512;  N = 1024; tt = bid - 2560; }
  else                 { W = ws.p[11]; Wt = W2t; K = 1024; N = 512;  tt = bid - 3072; }
  int ntiles = N >> 5;
  int bx = tt % ntiles, by = tt / ntiles;
  int n0 = bx * 32, k0 = by * 32;
  int tx = threadIdx.x & 31, ty = threadIdx.x >> 5;
#pragma unroll
  for (int i = 0; i < 32; i += 8)
    t[ty + i][tx] = W[(size_t)(k0 + ty + i) * N + n0 + tx];
  __syncthreads();
#pragma unroll
  for (int i = 0; i < 32; i += 8)
    Wt[(size_t)(n0 + ty + i) * K + k0 + tx] = f2b(t[tx][ty + i]);
}

// ---------------------------------------------------------------------------
// Dual LayerNorm: one wave per row of 512, writes bf16.
// ---------------------------------------------------------------------------
__global__ __launch_bounds__(256) void ln_kernel(const float* __restrict__ X0,
                                                 const float* __restrict__ X1,
                                                 const float* __restrict__ g0w,
                                                 const float* __restrict__ b0w,
                                                 const float* __restrict__ g1w,
                                                 const float* __restrict__ b1w,
                                                 unsigned short* __restrict__ out0,
                                                 unsigned short* __restrict__ out1) {
  int idx  = blockIdx.x * 4 + (threadIdx.x >> 6);
  int sel  = idx >> 14;
  int row  = idx & 16383;
  const float* X = sel ? X1 : X0;
  const float* gw = sel ? g1w : g0w;
  const float* bw = sel ? b1w : b0w;
  unsigned short* outB = sel ? out1 : out0;
  int lane = threadIdx.x & 63;
  const float4* xr = (const float4*)(X + (size_t)row * DM);
  float4 a = xr[lane];
  float4 c = xr[lane + 64];
  float s  = a.x + a.y + a.z + a.w + c.x + c.y + c.z + c.w;
  float s2 = a.x*a.x + a.y*a.y + a.z*a.z + a.w*a.w
           + c.x*c.x + c.y*c.y + c.z*c.z + c.w*c.w;
#pragma unroll
  for (int off = 1; off < 64; off <<= 1) {
    s  += __shfl_xor(s,  off, 64);
    s2 += __shfl_xor(s2, off, 64);
  }
  float mean = s * (1.0f / 512.0f);
  float var  = s2 * (1.0f / 512.0f) - mean * mean;
  float rstd = rsqrtf(var + 1e-6f);
  const float4* gv = (const float4*)gw;
  const float4* bv = (const float4*)bw;
  float4 g1 = gv[lane], g2 = gv[lane + 64];
  float4 b1 = bv[lane], b2 = bv[lane + 64];
  us4 o1, o2;
  o1.x = f2b((a.x - mean) * rstd * g1.x + b1.x);
  o1.y = f2b((a.y - mean) * rstd * g1.y + b1.y);
  o1.z = f2b((a.z - mean) * rstd * g1.z + b1.z);
  o1.w = f2b((a.w - mean) * rstd * g1.w + b1.w);
  o2.x = f2b((c.x - mean) * rstd * g2.x + b2.x);
  o2.y = f2b((c.y - mean) * rstd * g2.y + b2.y);
  o2.z = f2b((c.z - mean) * rstd * g2.z + b2.z);
  o2.w = f2b((c.w - mean) * rstd * g2.w + b2.w);
  *(us4*)(outB + (size_t)row * DM + lane * 4)        = o1;
  *(us4*)(outB + (size_t)row * DM + (lane + 64) * 4) = o2;
}

// ---------------------------------------------------------------------------
// bf16 MFMA GEMM: C[M,N] = A[M,K] @ Bt[N,K]^T + bias (+res)(gelu)
// XCD-affine grid; BK=64, double-buffered LDS (64KB), 2 blocks/CU; XOR-chunk
// swizzle folded into global source, same XOR on ds_read side.
// RES: 0 none, 1 fp32 residual, 2 bf16 residual.
// OMODE 0: bf16 out. 1: fp32 out. 3: self-QKV. 4: cross-QKV.
// ---------------------------------------------------------------------------
template <int RES, bool GELU_ACT, int OMODE>
__global__ __launch_bounds__(256, 2) void gemm_kernel(const unsigned short* __restrict__ A,
                                                      const unsigned short* __restrict__ A1,
                                                      const unsigned short* __restrict__ Bt,
                                                      const float* __restrict__ bias,
                                                      const void* __restrict__ res,
                                                      float* __restrict__ outF,
                                                      unsigned short* __restrict__ outB,
                                                      unsigned short* __restrict__ outV,
                                                      int M, int N, int K) {
  int nT = N >> 7;
  int mT = M >> 7;
  int xcd = blockIdx.x & 7;
  int idx = blockIdx.x >> 3;
  int mPerX = mT >> 3;
  int q = idx / nT;
  int tm = xcd * mPerX + q;
  int tn = idx - q * nT;
  int m0 = tm << 7, n0 = tn << 7;
  int tid = threadIdx.x, lane = tid & 63, w = tid >> 6;
  int m16 = lane & 15, q4 = lane >> 4;
  int wr = (w & 1) << 6, wc = (w >> 1) << 6;
  __shared__ unsigned short Alds[2][128 * 64];
  __shared__ unsigned short Blds[2][128 * 64];
  f32x4 acc[4][4] = {};

  const unsigned short* Aeff = A;
  const unsigned short* Bteff = Bt;
  const float* biaseff = bias;
  if (OMODE == 3) {
    int half = tm >> 7;
    Bteff = Bt + (size_t)half * 3 * 262144;
    biaseff = bias + half * 1536;
  }
  if (OMODE == 4) {
    if (tn >= 4) Aeff = A1;
  }

  // staging: lane owns row = it*32 + w*8 + (lane>>3), LDS chunk lane&7;
  // swizzle folded into global source col: chunk ^= row&7. Reads XOR same.
  int srow = lane >> 3;
  int scol = ((lane & 7) ^ srow) << 3;
  const unsigned short* Ag = Aeff  + (size_t)(m0 + w * 8 + srow) * K + scol;
  const unsigned short* Bg = Bteff + (size_t)(n0 + w * 8 + srow) * K + scol;
  int ldst = w * 512;

#pragma unroll
  for (int it = 0; it < 4; ++it) {
    gl_lds16(Ag + (size_t)it * 32 * K, Alds[0] + it * 2048 + ldst);
    gl_lds16(Bg + (size_t)it * 32 * K, Blds[0] + it * 2048 + ldst);
  }

  int nk = K >> 6;
  for (int ks = 0; ks < nk; ++ks) {
    int cur = ks & 1, nxt = cur ^ 1;
    __syncthreads();
    if (ks + 1 < nk) {
      int k0n = (ks + 1) << 6;
#pragma unroll
      for (int it = 0; it < 4; ++it) {
        gl_lds16(Ag + (size_t)it * 32 * K + k0n, Alds[nxt] + it * 2048 + ldst);
        gl_lds16(Bg + (size_t)it * 32 * K + k0n, Blds[nxt] + it * 2048 + ldst);
      }
    }
    const unsigned short* Ar = Alds[cur];
    const unsigned short* Br = Blds[cur];
#pragma unroll
    for (int kk = 0; kk < 64; kk += 32) {
      bf16x8 af[4], bfr[4];
#pragma unroll
      for (int i = 0; i < 4; ++i) {
        int row = wr + i * 16 + m16;
        af[i] = *(const bf16x8*)(Ar + row * 64 + ((((kk >> 3) + q4) ^ (m16 & 7)) << 3));
      }
#pragma unroll
      for (int j = 0; j < 4; ++j) {
        int row = wc + j * 16 + m16;
        bfr[j] = *(const bf16x8*)(Br + row * 64 + ((((kk >> 3) + q4) ^ (m16 & 7)) << 3));
      }
#pragma unroll
      for (int i = 0; i < 4; ++i)
#pragma unroll
        for (int j = 0; j < 4; ++j)
          acc[i][j] = __builtin_amdgcn_mfma_f32_16x16x32_bf16(af[i], bfr[j], acc[i][j], 0, 0, 0);
    }
  }
  // epilogue: C/D layout col=lane&15, row=(lane>>4)*4+reg
  if (OMODE == 3 || OMODE == 4) {
    if (n0 < 1024) {
      int stride = (OMODE == 3) ? 1024 : 512;
      unsigned short* ob = outB;
      int coff = 0;
      if (OMODE == 4 && n0 >= 512) { ob = outB + (size_t)MTOK * 512; coff = 512; }
      float sc = (n0 < 512) ? SC2 : 1.0f;     // fold softmax scale into Q
#pragma unroll
      for (int i = 0; i < 4; ++i) {
#pragma unroll
        for (int r = 0; r < 4; ++r) {
          int row = m0 + wr + i * 16 + q4 * 4 + r;
#pragma unroll
          for (int j = 0; j < 4; ++j) {
            int col = n0 + wc + j * 16 + m16;
            ob[(size_t)row * stride + col - coff] = f2b((acc[i][j][r] + biaseff[col]) * sc);
          }
        }
      }
    } else {
#pragma unroll
      for (int i = 0; i < 4; ++i) {
        int row0 = m0 + wr + i * 16 + q4 * 4;
        int s = row0 & 1023, bl = row0 >> 10;
        // key-permutation sigma: swap bit2 <-> bit3 of seq index (4-aligned
        // groups keep their us4 contiguity). PV contracts over this order.
        s = (s & ~12) | ((s & 4) << 1) | ((s & 8) >> 1);
#pragma unroll
        for (int j = 0; j < 4; ++j) {
          int col = n0 + wc + j * 16 + m16;
          int hh = (col - 1024) >> 7, hd = col & 127;
          float bb = biaseff[col];
          us4 pkv;
          pkv.x = f2b(acc[i][j][0] + bb);
          pkv.y = f2b(acc[i][j][1] + bb);
          pkv.z = f2b(acc[i][j][2] + bb);
          pkv.w = f2b(acc[i][j][3] + bb);
          *(us4*)(outV + (((size_t)(bl * 4 + hh)) * HDIM + hd) * SEQ + s) = pkv;
        }
      }
    }
  } else {
#pragma unroll
    for (int i = 0; i < 4; ++i) {
#pragma unroll
      for (int r = 0; r < 4; ++r) {
        int row = m0 + wr + i * 16 + q4 * 4 + r;
#pragma unroll
        for (int j = 0; j < 4; ++j) {
          int col = n0 + wc + j * 16 + m16;
          float v = acc[i][j][r] + bias[col];
          if (RES == 1) v += ((const float*)res)[(size_t)row * N + col];
          if (RES == 2) v += b2f(((const unsigned short*)res)[(size_t)row * N + col]);
          if (GELU_ACT) v = 0.5f * v * (1.0f + erff(v * 0.70710678118654752f));
          if (OMODE == 1) outF[(size_t)row * N + col] = v;
          else            outB[(size_t)row * N + col] = f2b(v);
        }
      }
    }
  }
}

// ---------------------------------------------------------------------------
// Fused attention, S^T formulation, register-P, double-buffered staging.
// KVBLK=64, 64KB LDS, 2 blocks/CU (L2 pair budget: 8 pairs x 512KB = 4MB
// per XCD -- do NOT raise occupancy here, see R8 note). No setprio (R9
// regression: lockstep waves). V is pre-permuted (key bit2<->3) so the S^T
// C-layout registers ARE the PV A-operand fragments.
// ---------------------------------------------------------------------------
__global__ __launch_bounds__(256, 2) void attn_kernel(const unsigned short* __restrict__ Qb_,
                                                      const unsigned short* __restrict__ Kb_,
                                                      int tstride,
                                                      const unsigned short* __restrict__ Vt,
                                                      unsigned short* __restrict__ CTX,
                                                      int pairs_per_xcd) {
  int xcd = blockIdx.x & 7;
  int i   = blockIdx.x >> 3;
  int pair = xcd * pairs_per_xcd + (i >> 3);
  int qt   = i & 7;
  int b = pair >> 2, h = pair & 3;
  int tid = threadIdx.x, lane = tid & 63, w = tid >> 6;
  int m32 = lane & 31, hf = lane >> 5;
  size_t qkoff = ((size_t)b * SEQ) * tstride + h * HDIM;
  const unsigned short* Qg = Qb_ + qkoff;
  const unsigned short* Kg = Kb_ + qkoff;
  const unsigned short* Vp = Vt + (size_t)pair * HDIM * SEQ;

  __shared__ unsigned short Klds[2][64 * 128];   // [key][hd], chunk-swizzled
  __shared__ unsigned short Vlds[2][128 * 64];   // [hd][slot], chunk-swizzled

  int qrow0 = qt * 128 + w * 32;
  bf16x8 qf[8];   // Q[q=qrow0+m32][hd=ks*16+hf*8+j]  (B-operand frags)
  {
    const unsigned short* qp = Qg + (size_t)(qrow0 + m32) * tstride + hf * 8;
#pragma unroll
    for (int ks = 0; ks < 8; ++ks) qf[ks] = *(const bf16x8*)(qp + ks * 16);
  }
  bf16x8 onesf;
#pragma unroll
  for (int j = 0; j < 8; ++j) onesf[j] = (short)0x3F80;  // bf16 1.0

  // staging source addresses (XOR-chunk swizzle folded into global address)
  const unsigned short* kp0 = Kg + (size_t)(16 * w + (lane >> 4)) * tstride
                              + (((lane & 15) ^ (lane >> 4)) << 3);
  const unsigned short* kp1 = Kg + (size_t)(16 * w + 4 + (lane >> 4)) * tstride
                              + (((lane & 15) ^ ((lane >> 4) + 4)) << 3);
  const unsigned short* vp0 = Vp + (size_t)(32 * w + (lane >> 3)) * SEQ
                              + (((lane & 7) ^ (lane >> 3)) << 3);
  int klo = 16 * w * 128;
  int vlo = 32 * w * 64;

  // prologue: stage ktile 0 into buffer 0
  gl_lds16(kp0,               Klds[0] + klo);
  gl_lds16(kp1,               Klds[0] + klo + 4 * 128);
  gl_lds16(kp0 + 8 * tstride, Klds[0] + klo + 8 * 128);
  gl_lds16(kp1 + 8 * tstride, Klds[0] + klo + 12 * 128);
  gl_lds16(vp0,               Vlds[0] + vlo);
  gl_lds16(vp0 + 8 * SEQ,     Vlds[0] + vlo + 8 * 64);
  gl_lds16(vp0 + 16 * SEQ,    Vlds[0] + vlo + 16 * 64);
  gl_lds16(vp0 + 24 * SEQ,    Vlds[0] + vlo + 24 * 64);

  f32x16 o0 = {}, o1 = {}, o2 = {}, o3 = {};
  f32x16 lacc = {};

  for (int kt = 0; kt < 16; ++kt) {
    int cur = kt & 1, nxt = cur ^ 1;
    __syncthreads();   // buf[cur] ready; all waves done with buf[nxt]
    if (kt < 15) {     // stage ktile kt+1 into buf[nxt]
      kp0 += 64 * tstride; kp1 += 64 * tstride; vp0 += 64;
      gl_lds16(kp0,               Klds[nxt] + klo);
      gl_lds16(kp1,               Klds[nxt] + klo + 4 * 128);
      gl_lds16(kp0 + 8 * tstride, Klds[nxt] + klo + 8 * 128);
      gl_lds16(kp1 + 8 * tstride, Klds[nxt] + klo + 12 * 128);
      gl_lds16(vp0,               Vlds[nxt] + vlo);
      gl_lds16(vp0 + 8 * SEQ,     Vlds[nxt] + vlo + 8 * 64);
      gl_lds16(vp0 + 16 * SEQ,    Vlds[nxt] + vlo + 16 * 64);
      gl_lds16(vp0 + 24 * SEQ,    Vlds[nxt] + vlo + 24 * 64);
    }
    const unsigned short* Kr = Klds[cur];
    const unsigned short* Vr = Vlds[cur];

    // S^T = K · Q^T : A = K-frags (m=key), B = Q-frags (registers)
    f32x16 sc0 = {}, sc1 = {};
#pragma unroll
    for (int ks = 0; ks < 8; ++ks) {
      int ch = 2 * ks + hf;
      bf16x8 kf0 = *(const bf16x8*)(Kr + m32 * 128 + ((ch ^ (m32 & 7)) << 3));
      sc0 = __builtin_amdgcn_mfma_f32_32x32x16_bf16(kf0, qf[ks], sc0, 0, 0, 0);
      int k1r = 32 + m32;
      bf16x8 kf1 = *(const bf16x8*)(Kr + k1r * 128 + ((ch ^ (k1r & 7)) << 3));
      sc1 = __builtin_amdgcn_mfma_f32_32x32x16_bf16(kf1, qf[ks], sc1, 0, 0, 0);
    }

    // P = exp2(S) (Q pre-scaled). With sigma-permuted V, the C-layout regs
    // are already A-frag order: pa[ks] = pack(sc regs 8ks..8ks+7).
    bf16x8 pa[4];
#pragma unroll
    for (int t = 0; t < 2; ++t) {
      const f32x16& sc = t ? sc1 : sc0;
#pragma unroll
      for (int g = 0; g < 2; ++g) {
        union { unsigned u[4]; bf16x8 v; } uu;
        uu.u[0] = pk2t(ex2(sc[8*g+0]), ex2(sc[8*g+1]));
        uu.u[1] = pk2t(ex2(sc[8*g+2]), ex2(sc[8*g+3]));
        uu.u[2] = pk2t(ex2(sc[8*g+4]), ex2(sc[8*g+5]));
        uu.u[3] = pk2t(ex2(sc[8*g+6]), ex2(sc[8*g+7]));
        pa[2*t + g] = uu.v;
      }
    }

    // O += P · V ; l += P · ones  (lacc C-layout matches O C-layout)
#pragma unroll
    for (int ks = 0; ks < 4; ++ks) {
      int ch = 2 * ks + hf;
      int sw = m32 & 7;
      lacc = __builtin_amdgcn_mfma_f32_32x32x16_bf16(pa[ks], onesf, lacc, 0, 0, 0);
      {
        bf16x8 vf = *(const bf16x8*)(Vr + m32 * 64 + ((ch ^ sw) << 3));
        o0 = __builtin_amdgcn_mfma_f32_32x32x16_bf16(pa[ks], vf, o0, 0, 0, 0);
      }
      {
        bf16x8 vf = *(const bf16x8*)(Vr + (32 + m32) * 64 + ((ch ^ sw) << 3));
        o1 = __builtin_amdgcn_mfma_f32_32x32x16_bf16(pa[ks], vf, o1, 0, 0, 0);
      }
      {
        bf16x8 vf = *(const bf16x8*)(Vr + (64 + m32) * 64 + ((ch ^ sw) << 3));
        o2 = __builtin_amdgcn_mfma_f32_32x32x16_bf16(pa[ks], vf, o2, 0, 0, 0);
      }
      {
        bf16x8 vf = *(const bf16x8*)(Vr + (96 + m32) * 64 + ((ch ^ sw) << 3));
        o3 = __builtin_amdgcn_mfma_f32_32x32x16_bf16(pa[ks], vf, o3, 0, 0, 0);
      }
    }
  }

  // store O normalized; lacc[reg] holds l for row (reg&3)+8*(reg>>2)+4*hf
  size_t obase = ((size_t)b * SEQ + qrow0) * DM + h * HDIM;
#pragma unroll
  for (int g = 0; g < 4; ++g) {
#pragma unroll
    for (int r = 0; r < 4; ++r) {
      int reg = 4 * g + r;
      int rowl = 8 * g + 4 * hf + r;
      float inv = 1.0f / lacc[reg];
      size_t off = obase + (size_t)rowl * DM + m32;
      CTX[off]      = f2b(o0[reg] * inv);
      CTX[off + 32] = f2b(o1[reg] * inv);
      CTX[off + 64] = f2b(o2[reg] * inv);
      CTX[off + 96] = f2b(o3[reg] * inv);
    }
  }
}

// ---------------------------------------------------------------------------
extern "C" void kernel_launch(void* const* d_in, const int* in_sizes, int n_in,
                              void* d_out, int out_size, void* d_ws, size_t ws_size,
                              hipStream_t stream) {
  const float* x1    = (const float*)d_in[0];
  const float* x2    = (const float*)d_in[1];
  const float* ln1_g = (const float*)d_in[2];
  const float* ln1_b = (const float*)d_in[3];
  const float* ln2_g = (const float*)d_in[4];
  const float* ln2_b = (const float*)d_in[5];
  const float* lnf_g = (const float*)d_in[6];
  const float* lnf_b = (const float*)d_in[7];
  P12 wsrc;
  for (int i = 0; i < 10; ++i) wsrc.p[i] = (const float*)d_in[8 + 2 * i];
  wsrc.p[10] = (const float*)d_in[28];   // W1
  wsrc.p[11] = (const float*)d_in[30];   // W2
  P9 bsrc;
  for (int i = 0; i < 9; ++i) bsrc.p[i] = (const float*)d_in[9 + 2 * i];
  const float* bo   = (const float*)d_in[27];
  const float* b1   = (const float*)d_in[29];
  const float* b2   = (const float*)d_in[31];

  char* ws = (char*)d_ws;
  size_t off = 0;
  auto alloc = [&](size_t bytes) -> char* {
    char* p = ws + off;
    off += (bytes + 255) & ~(size_t)255;
    return p;
  };
  unsigned short* WT0 = (unsigned short*)alloc((size_t)10 * 512 * 512 * 2);
  auto WT = [&](int i) { return WT0 + (size_t)i * 262144; };
  unsigned short* W1t = (unsigned short*)alloc((size_t)1024 * 512 * 2);
  unsigned short* W2t = (unsigned short*)alloc((size_t)512 * 1024 * 2);
  float*          bcc = (float*)alloc(4608 * 4);
  unsigned short* XN  = (unsigned short*)alloc((size_t)2 * MTOK * DM * 2);
  unsigned short* QKb = (unsigned short*)alloc((size_t)2 * MTOK * 1024 * 2);
  unsigned short* Vtb = (unsigned short*)alloc((size_t)128 * HDIM * SEQ * 2);
  unsigned short* CT  = (unsigned short*)alloc((size_t)2 * MTOK * DM * 2);
  float*          Xf  = (float*)alloc((size_t)MTOK * DM * 4);
  unsigned short* XN1 = XN + (size_t)MTOK * DM;
  unsigned short* MID = QKb;                       // alias (Q12/K12 dead)
  unsigned short* HN  = Vtb;                       // alias (Vt dead)
  float* bias_self  = bcc;                         // [2][1536]
  float* bias_cross = bcc + 3072;                  // [1536]

  // 0) prep: 12 weight transposes + bias concat, one dispatch
  prep_kernel<<<3602, 256, 0, stream>>>(wsrc, bsrc, WT0, W1t, W2t, bcc);

  // 1) both LayerNorms
  ln_kernel<<<2 * MTOK / 4, 256, 0, stream>>>(x1, x2, ln1_g, ln1_b, ln2_g, ln2_b, XN, XN1);

  // 2) self QKV, both streams, one dispatch: M=32768, N=1536 (Q pre-scaled)
  gemm_kernel<0, false, 3><<<3072, 256, 0, stream>>>(XN, nullptr, WT0, bias_self,
      nullptr, nullptr, QKb, Vtb, 32768, 1536, 512);

  // 3) self-attention, both streams: 128 pairs
  attn_kernel<<<128 * 8, 256, 0, stream>>>(QKb, QKb + 512, 1024, Vtb, CT, 16);

  // 4) out-proj + bias + residual(xn) -> src (in-place over XN, bf16)
  gemm_kernel<2, false, 0><<<1024, 256, 0, stream>>>(CT, nullptr, WT(9), bo, XN,
      nullptr, XN, nullptr, 32768, 512, 512);

  // 5) cross QKV, one dispatch: Q from src1(XN), K/V from src2(XN1)
  gemm_kernel<0, false, 4><<<1536, 256, 0, stream>>>(XN, XN1, WT(6), bias_cross,
      nullptr, nullptr, QKb, Vtb, 16384, 1536, 512);

  // 6) cross-attention: 64 pairs
  attn_kernel<<<64 * 8, 256, 0, stream>>>(QKb, QKb + (size_t)MTOK * 512, 512, Vtb, CT, 8);

  // 7) out-proj + bias + residual(identity x1, fp32) -> x (fp32)
  gemm_kernel<1, false, 1><<<512, 256, 0, stream>>>(CT, nullptr, WT(9), bo, x1,
      Xf, nullptr, nullptr, 16384, 512, 512);

  // 8) final LN
  ln_kernel<<<MTOK / 4, 256, 0, stream>>>(Xf, Xf, lnf_g, lnf_b, lnf_g, lnf_b, HN, HN);

  // 9) MLP: gelu(h@W1+b1) -> MID ; MID@W2+b2 + x -> out (fp32)
  gemm_kernel<0, true,  0><<<1024, 256, 0, stream>>>(HN, nullptr, W1t, b1,
      nullptr, nullptr, MID, nullptr, 16384, 1024, 512);
  gemm_kernel<1, false, 1><<<512, 256, 0, stream>>>(MID, nullptr, W2t, b2,
      Xf, (float*)d_out, nullptr, nullptr, 16384, 512, 1024);
}

// Round 5
// 506.537 us; speedup vs baseline: 1.4032x; 1.0168x over previous
//
#include <hip/hip_runtime.h>
#include <math.h>

// ---------------------------------------------------------------------------
// Block_42167988912800: dual-stream transformer block on gfx950.
// B=16 S=1024 D=512 H=4 hd=128 MLP=1024, fp32 in/out, bf16 MFMA compute.
// R6: XCD-affine GEMM grid mapping.
// R7: GEMM XOR-chunk LDS swizzle + double-buffered staging (BK=64, 2 blk/CU).
// R8: FAILED: attn KVBLK=32 @ 4 blk/CU blew per-XCD L2 pair budget -> HBM-bound.
// R9: FAILED both: attn setprio; GEMM BK=32. Reverted.
// R10: attn exp2f -> raw v_exp_f32: 92.8 -> 84.5us (VALUBusy 44->26).
// R11: attn software pipeline. Measured pipes SERIALIZED (MFMA 40% + VALU 26%
//     + LDS ~36% ~= 100% of runtime): per-kt chain read->QK->exp->PV between
//     lockstep barriers leaves every pipe idle 60%. Restructure: per iter,
//     QK(t+1) from buf[nxt] runs alongside PV(t) from buf[cur] and exp(t+1)
//     fills MFMA drain slots (T15 att[2] pattern). Two barriers/iter:
//     A = tile t+1 staged; B = all waves done with buf[cur] before it is
//     restaged with tile t+2. Two static P-sets pa/pb (no runtime indexing).
// ---------------------------------------------------------------------------

#define SEQ   1024
#define DM    512
#define HDIM  128
#define MTOK  16384
#define MLPD  1024
#define SC2   ((float)(0.08838834764831845 * 1.4426950408889634))  // scale*log2e

typedef short bf16x8 __attribute__((ext_vector_type(8)));
typedef float f32x4  __attribute__((ext_vector_type(4)));
typedef float f32x16 __attribute__((ext_vector_type(16)));
typedef unsigned short us4 __attribute__((ext_vector_type(4)));

typedef unsigned int u32g __attribute__((address_space(1)));
typedef unsigned int u32l __attribute__((address_space(3)));

static __device__ __forceinline__ unsigned short f2b(float f) {
  union { float f; unsigned u; } v; v.f = f;
  unsigned r = v.u + 0x7FFFu + ((v.u >> 16) & 1u);
  return (unsigned short)(r >> 16);
}
static __device__ __forceinline__ float b2f(unsigned short h) {
  union { unsigned u; float f; } v; v.u = ((unsigned)h) << 16;
  return v.f;
}
// truncating pack: two floats -> two bf16 in one u32 [lo=a, hi=b]
static __device__ __forceinline__ unsigned pk2t(float a, float b) {
  union { float f; unsigned u; } va, vb; va.f = a; vb.f = b;
  return __builtin_amdgcn_perm(vb.u, va.u, 0x07060302u);
}
// raw 2^x: v_exp_f32, no libm guard sequence (inputs bounded, pre-scaled)
static __device__ __forceinline__ float ex2(float x) {
  float r; asm("v_exp_f32 %0, %1" : "=v"(r) : "v"(x)); return r;
}
static __device__ __forceinline__ void gl_lds16(const void* g, void* l) {
  __builtin_amdgcn_global_load_lds((u32g*)g, (u32l*)l, 16, 0, 0);
}

// ---------------------------------------------------------------------------
// Prep: 12 weight transposes (fp32 [K][N] -> bf16 [N][K]) + 9-bias concat.
// ---------------------------------------------------------------------------
struct P12 { const float* p[12]; };
struct P9  { const float* p[9]; };

__global__ __launch_bounds__(256) void prep_kernel(P12 ws, P9 bs,
                                                   unsigned short* __restrict__ WT0,
                                                   unsigned short* __restrict__ W1t,
                                                   unsigned short* __restrict__ W2t,
                                                   float* __restrict__ bcc) {
  int bid = blockIdx.x;
  if (bid >= 3584) {
    int i = (bid - 3584) * 256 + threadIdx.x;
    if (i < 4608) bcc[i] = bs.p[i >> 9][i & 511];
    return;
  }
  __shared__ float t[32][33];
  const float* W; unsigned short* Wt; int K, N, tt;
  if (bid < 2560)      { int wi = bid >> 8; W = ws.p[wi]; Wt = WT0 + (size_t)wi * 262144; K = 512; N = 512; tt = bid & 255; }
  else if (bid < 3072) { W = ws.p[10]; Wt = W1t; K = 512;  N = 1024; tt = bid - 2560; }
  else                 { W = ws.p[11]; Wt = W2t; K = 1024; N = 512;  tt = bid - 3072; }
  int ntiles = N >> 5;
  int bx = tt % ntiles, by = tt / ntiles;
  int n0 = bx * 32, k0 = by * 32;
  int tx = threadIdx.x & 31, ty = threadIdx.x >> 5;
#pragma unroll
  for (int i = 0; i < 32; i += 8)
    t[ty + i][tx] = W[(size_t)(k0 + ty + i) * N + n0 + tx];
  __syncthreads();
#pragma unroll
  for (int i = 0; i < 32; i += 8)
    Wt[(size_t)(n0 + ty + i) * K + k0 + tx] = f2b(t[tx][ty + i]);
}

// ---------------------------------------------------------------------------
// Dual LayerNorm: one wave per row of 512, writes bf16.
// ---------------------------------------------------------------------------
__global__ __launch_bounds__(256) void ln_kernel(const float* __restrict__ X0,
                                                 const float* __restrict__ X1,
                                                 const float* __restrict__ g0w,
                                                 const float* __restrict__ b0w,
                                                 const float* __restrict__ g1w,
                                                 const float* __restrict__ b1w,
                                                 unsigned short* __restrict__ out0,
                                                 unsigned short* __restrict__ out1) {
  int idx  = blockIdx.x * 4 + (threadIdx.x >> 6);
  int sel  = idx >> 14;
  int row  = idx & 16383;
  const float* X = sel ? X1 : X0;
  const float* gw = sel ? g1w : g0w;
  const float* bw = sel ? b1w : b0w;
  unsigned short* outB = sel ? out1 : out0;
  int lane = threadIdx.x & 63;
  const float4* xr = (const float4*)(X + (size_t)row * DM);
  float4 a = xr[lane];
  float4 c = xr[lane + 64];
  float s  = a.x + a.y + a.z + a.w + c.x + c.y + c.z + c.w;
  float s2 = a.x*a.x + a.y*a.y + a.z*a.z + a.w*a.w
           + c.x*c.x + c.y*c.y + c.z*c.z + c.w*c.w;
#pragma unroll
  for (int off = 1; off < 64; off <<= 1) {
    s  += __shfl_xor(s,  off, 64);
    s2 += __shfl_xor(s2, off, 64);
  }
  float mean = s * (1.0f / 512.0f);
  float var  = s2 * (1.0f / 512.0f) - mean * mean;
  float rstd = rsqrtf(var + 1e-6f);
  const float4* gv = (const float4*)gw;
  const float4* bv = (const float4*)bw;
  float4 g1 = gv[lane], g2 = gv[lane + 64];
  float4 b1 = bv[lane], b2 = bv[lane + 64];
  us4 o1, o2;
  o1.x = f2b((a.x - mean) * rstd * g1.x + b1.x);
  o1.y = f2b((a.y - mean) * rstd * g1.y + b1.y);
  o1.z = f2b((a.z - mean) * rstd * g1.z + b1.z);
  o1.w = f2b((a.w - mean) * rstd * g1.w + b1.w);
  o2.x = f2b((c.x - mean) * rstd * g2.x + b2.x);
  o2.y = f2b((c.y - mean) * rstd * g2.y + b2.y);
  o2.z = f2b((c.z - mean) * rstd * g2.z + b2.z);
  o2.w = f2b((c.w - mean) * rstd * g2.w + b2.w);
  *(us4*)(outB + (size_t)row * DM + lane * 4)        = o1;
  *(us4*)(outB + (size_t)row * DM + (lane + 64) * 4) = o2;
}

// ---------------------------------------------------------------------------
// bf16 MFMA GEMM: C[M,N] = A[M,K] @ Bt[N,K]^T + bias (+res)(gelu)
// XCD-affine grid; BK=64, double-buffered LDS (64KB), 2 blocks/CU; XOR-chunk
// swizzle folded into global source, same XOR on ds_read side.
// RES: 0 none, 1 fp32 residual, 2 bf16 residual.
// OMODE 0: bf16 out. 1: fp32 out. 3: self-QKV. 4: cross-QKV.
// ---------------------------------------------------------------------------
template <int RES, bool GELU_ACT, int OMODE>
__global__ __launch_bounds__(256, 2) void gemm_kernel(const unsigned short* __restrict__ A,
                                                      const unsigned short* __restrict__ A1,
                                                      const unsigned short* __restrict__ Bt,
                                                      const float* __restrict__ bias,
                                                      const void* __restrict__ res,
                                                      float* __restrict__ outF,
                                                      unsigned short* __restrict__ outB,
                                                      unsigned short* __restrict__ outV,
                                                      int M, int N, int K) {
  int nT = N >> 7;
  int mT = M >> 7;
  int xcd = blockIdx.x & 7;
  int idx = blockIdx.x >> 3;
  int mPerX = mT >> 3;
  int q = idx / nT;
  int tm = xcd * mPerX + q;
  int tn = idx - q * nT;
  int m0 = tm << 7, n0 = tn << 7;
  int tid = threadIdx.x, lane = tid & 63, w = tid >> 6;
  int m16 = lane & 15, q4 = lane >> 4;
  int wr = (w & 1) << 6, wc = (w >> 1) << 6;
  __shared__ unsigned short Alds[2][128 * 64];
  __shared__ unsigned short Blds[2][128 * 64];
  f32x4 acc[4][4] = {};

  const unsigned short* Aeff = A;
  const unsigned short* Bteff = Bt;
  const float* biaseff = bias;
  if (OMODE == 3) {
    int half = tm >> 7;
    Bteff = Bt + (size_t)half * 3 * 262144;
    biaseff = bias + half * 1536;
  }
  if (OMODE == 4) {
    if (tn >= 4) Aeff = A1;
  }

  // staging: lane owns row = it*32 + w*8 + (lane>>3), LDS chunk lane&7;
  // swizzle folded into global source col: chunk ^= row&7. Reads XOR same.
  int srow = lane >> 3;
  int scol = ((lane & 7) ^ srow) << 3;
  const unsigned short* Ag = Aeff  + (size_t)(m0 + w * 8 + srow) * K + scol;
  const unsigned short* Bg = Bteff + (size_t)(n0 + w * 8 + srow) * K + scol;
  int ldst = w * 512;

#pragma unroll
  for (int it = 0; it < 4; ++it) {
    gl_lds16(Ag + (size_t)it * 32 * K, Alds[0] + it * 2048 + ldst);
    gl_lds16(Bg + (size_t)it * 32 * K, Blds[0] + it * 2048 + ldst);
  }

  int nk = K >> 6;
  for (int ks = 0; ks < nk; ++ks) {
    int cur = ks & 1, nxt = cur ^ 1;
    __syncthreads();
    if (ks + 1 < nk) {
      int k0n = (ks + 1) << 6;
#pragma unroll
      for (int it = 0; it < 4; ++it) {
        gl_lds16(Ag + (size_t)it * 32 * K + k0n, Alds[nxt] + it * 2048 + ldst);
        gl_lds16(Bg + (size_t)it * 32 * K + k0n, Blds[nxt] + it * 2048 + ldst);
      }
    }
    const unsigned short* Ar = Alds[cur];
    const unsigned short* Br = Blds[cur];
#pragma unroll
    for (int kk = 0; kk < 64; kk += 32) {
      bf16x8 af[4], bfr[4];
#pragma unroll
      for (int i = 0; i < 4; ++i) {
        int row = wr + i * 16 + m16;
        af[i] = *(const bf16x8*)(Ar + row * 64 + ((((kk >> 3) + q4) ^ (m16 & 7)) << 3));
      }
#pragma unroll
      for (int j = 0; j < 4; ++j) {
        int row = wc + j * 16 + m16;
        bfr[j] = *(const bf16x8*)(Br + row * 64 + ((((kk >> 3) + q4) ^ (m16 & 7)) << 3));
      }
#pragma unroll
      for (int i = 0; i < 4; ++i)
#pragma unroll
        for (int j = 0; j < 4; ++j)
          acc[i][j] = __builtin_amdgcn_mfma_f32_16x16x32_bf16(af[i], bfr[j], acc[i][j], 0, 0, 0);
    }
  }
  // epilogue: C/D layout col=lane&15, row=(lane>>4)*4+reg
  if (OMODE == 3 || OMODE == 4) {
    if (n0 < 1024) {
      int stride = (OMODE == 3) ? 1024 : 512;
      unsigned short* ob = outB;
      int coff = 0;
      if (OMODE == 4 && n0 >= 512) { ob = outB + (size_t)MTOK * 512; coff = 512; }
      float sc = (n0 < 512) ? SC2 : 1.0f;     // fold softmax scale into Q
#pragma unroll
      for (int i = 0; i < 4; ++i) {
#pragma unroll
        for (int r = 0; r < 4; ++r) {
          int row = m0 + wr + i * 16 + q4 * 4 + r;
#pragma unroll
          for (int j = 0; j < 4; ++j) {
            int col = n0 + wc + j * 16 + m16;
            ob[(size_t)row * stride + col - coff] = f2b((acc[i][j][r] + biaseff[col]) * sc);
          }
        }
      }
    } else {
#pragma unroll
      for (int i = 0; i < 4; ++i) {
        int row0 = m0 + wr + i * 16 + q4 * 4;
        int s = row0 & 1023, bl = row0 >> 10;
        // key-permutation sigma: swap bit2 <-> bit3 of seq index (4-aligned
        // groups keep their us4 contiguity). PV contracts over this order.
        s = (s & ~12) | ((s & 4) << 1) | ((s & 8) >> 1);
#pragma unroll
        for (int j = 0; j < 4; ++j) {
          int col = n0 + wc + j * 16 + m16;
          int hh = (col - 1024) >> 7, hd = col & 127;
          float bb = biaseff[col];
          us4 pkv;
          pkv.x = f2b(acc[i][j][0] + bb);
          pkv.y = f2b(acc[i][j][1] + bb);
          pkv.z = f2b(acc[i][j][2] + bb);
          pkv.w = f2b(acc[i][j][3] + bb);
          *(us4*)(outV + (((size_t)(bl * 4 + hh)) * HDIM + hd) * SEQ + s) = pkv;
        }
      }
    }
  } else {
#pragma unroll
    for (int i = 0; i < 4; ++i) {
#pragma unroll
      for (int r = 0; r < 4; ++r) {
        int row = m0 + wr + i * 16 + q4 * 4 + r;
#pragma unroll
        for (int j = 0; j < 4; ++j) {
          int col = n0 + wc + j * 16 + m16;
          float v = acc[i][j][r] + bias[col];
          if (RES == 1) v += ((const float*)res)[(size_t)row * N + col];
          if (RES == 2) v += b2f(((const unsigned short*)res)[(size_t)row * N + col]);
          if (GELU_ACT) v = 0.5f * v * (1.0f + erff(v * 0.70710678118654752f));
          if (OMODE == 1) outF[(size_t)row * N + col] = v;
          else            outB[(size_t)row * N + col] = f2b(v);
        }
      }
    }
  }
}

// ---------------------------------------------------------------------------
// Fused attention, S^T formulation, register-P, software-pipelined (R11).
// KVBLK=64, 64KB LDS, 2 blocks/CU (L2 pair budget: 8 pairs x 512KB = 4MB
// per XCD -- do NOT raise occupancy, R8). Per iteration:
//   barrier_A (tile t+1 staged) ; QK(t+1) from nxt || PV(t) from cur ||
//   exp(t+1) ; barrier_B (cur free) ; stage(t+2 -> cur).
// V is pre-permuted (key bit2<->3) so S^T C-layout regs ARE PV A-frags.
// ---------------------------------------------------------------------------
__global__ __launch_bounds__(256, 2) void attn_kernel(const unsigned short* __restrict__ Qb_,
                                                      const unsigned short* __restrict__ Kb_,
                                                      int tstride,
                                                      const unsigned short* __restrict__ Vt,
                                                      unsigned short* __restrict__ CTX,
                                                      int pairs_per_xcd) {
  int xcd = blockIdx.x & 7;
  int i   = blockIdx.x >> 3;
  int pair = xcd * pairs_per_xcd + (i >> 3);
  int qt   = i & 7;
  int b = pair >> 2, h = pair & 3;
  int tid = threadIdx.x, lane = tid & 63, w = tid >> 6;
  int m32 = lane & 31, hf = lane >> 5;
  size_t qkoff = ((size_t)b * SEQ) * tstride + h * HDIM;
  const unsigned short* Qg = Qb_ + qkoff;
  const unsigned short* Kg = Kb_ + qkoff;
  const unsigned short* Vp = Vt + (size_t)pair * HDIM * SEQ;

  __shared__ unsigned short Klds[2][64 * 128];   // [key][hd], chunk-swizzled
  __shared__ unsigned short Vlds[2][128 * 64];   // [hd][slot], chunk-swizzled

  int qrow0 = qt * 128 + w * 32;
  bf16x8 qf[8];   // Q[q=qrow0+m32][hd=ks*16+hf*8+j]  (B-operand frags)
  {
    const unsigned short* qp = Qg + (size_t)(qrow0 + m32) * tstride + hf * 8;
#pragma unroll
    for (int ks = 0; ks < 8; ++ks) qf[ks] = *(const bf16x8*)(qp + ks * 16);
  }
  bf16x8 onesf;
#pragma unroll
  for (int j = 0; j < 8; ++j) onesf[j] = (short)0x3F80;  // bf16 1.0

  // staging source addresses (XOR-chunk swizzle folded into global address)
  const unsigned short* kp0 = Kg + (size_t)(16 * w + (lane >> 4)) * tstride
                              + (((lane & 15) ^ (lane >> 4)) << 3);
  const unsigned short* kp1 = Kg + (size_t)(16 * w + 4 + (lane >> 4)) * tstride
                              + (((lane & 15) ^ ((lane >> 4) + 4)) << 3);
  const unsigned short* vp0 = Vp + (size_t)(32 * w + (lane >> 3)) * SEQ
                              + (((lane & 7) ^ (lane >> 3)) << 3);
  int klo = 16 * w * 128;
  int vlo = 32 * w * 64;

  auto stage = [&](unsigned short* Kb, unsigned short* Vb) {
    gl_lds16(kp0,               Kb + klo);
    gl_lds16(kp1,               Kb + klo + 4 * 128);
    gl_lds16(kp0 + 8 * tstride, Kb + klo + 8 * 128);
    gl_lds16(kp1 + 8 * tstride, Kb + klo + 12 * 128);
    gl_lds16(vp0,               Vb + vlo);
    gl_lds16(vp0 + 8 * SEQ,     Vb + vlo + 8 * 64);
    gl_lds16(vp0 + 16 * SEQ,    Vb + vlo + 16 * 64);
    gl_lds16(vp0 + 24 * SEQ,    Vb + vlo + 24 * 64);
  };
  auto adv = [&]() { kp0 += 64 * tstride; kp1 += 64 * tstride; vp0 += 64; };

  f32x16 o0 = {}, o1 = {}, o2 = {}, o3 = {};
  f32x16 lacc = {};
  bf16x8 pa0, pa1, pa2, pa3;       // P(t)   bf16 A-frags
  bf16x8 pb0, pb1, pb2, pb3;       // P(t+1)

  // QK: S^T = K.Q^T, A = K-frags from LDS, B = Q-frags (registers)
  auto qk = [&](const unsigned short* Kr, f32x16& s0, f32x16& s1) {
#pragma unroll
    for (int ks = 0; ks < 8; ++ks) {
      int ch = 2 * ks + hf;
      bf16x8 kf0 = *(const bf16x8*)(Kr + m32 * 128 + ((ch ^ (m32 & 7)) << 3));
      s0 = __builtin_amdgcn_mfma_f32_32x32x16_bf16(kf0, qf[ks], s0, 0, 0, 0);
      int k1r = 32 + m32;
      bf16x8 kf1 = *(const bf16x8*)(Kr + k1r * 128 + ((ch ^ (k1r & 7)) << 3));
      s1 = __builtin_amdgcn_mfma_f32_32x32x16_bf16(kf1, qf[ks], s1, 0, 0, 0);
    }
  };
  // exp2 + pack to bf16 A-frag order (sigma-permuted V makes this direct)
  auto mkpa = [&](const f32x16& s0, const f32x16& s1,
                  bf16x8& q0, bf16x8& q1, bf16x8& q2, bf16x8& q3) {
    union { unsigned u[4]; bf16x8 v; } uu;
#pragma unroll
    for (int g = 0; g < 2; ++g) {
      uu.u[0] = pk2t(ex2(s0[8*g+0]), ex2(s0[8*g+1]));
      uu.u[1] = pk2t(ex2(s0[8*g+2]), ex2(s0[8*g+3]));
      uu.u[2] = pk2t(ex2(s0[8*g+4]), ex2(s0[8*g+5]));
      uu.u[3] = pk2t(ex2(s0[8*g+6]), ex2(s0[8*g+7]));
      if (g == 0) q0 = uu.v; else q1 = uu.v;
    }
#pragma unroll
    for (int g = 0; g < 2; ++g) {
      uu.u[0] = pk2t(ex2(s1[8*g+0]), ex2(s1[8*g+1]));
      uu.u[1] = pk2t(ex2(s1[8*g+2]), ex2(s1[8*g+3]));
      uu.u[2] = pk2t(ex2(s1[8*g+4]), ex2(s1[8*g+5]));
      uu.u[3] = pk2t(ex2(s1[8*g+6]), ex2(s1[8*g+7]));
      if (g == 0) q2 = uu.v; else q3 = uu.v;
    }
  };
  // PV: O += P.V ; l += P.ones
  auto pv = [&](const unsigned short* Vr,
                const bf16x8& q0, const bf16x8& q1, const bf16x8& q2, const bf16x8& q3) {
#pragma unroll
    for (int ks = 0; ks < 4; ++ks) {
      const bf16x8& pk = (ks == 0) ? q0 : (ks == 1) ? q1 : (ks == 2) ? q2 : q3;
      int ch = 2 * ks + hf;
      int sw = m32 & 7;
      lacc = __builtin_amdgcn_mfma_f32_32x32x16_bf16(pk, onesf, lacc, 0, 0, 0);
      {
        bf16x8 vf = *(const bf16x8*)(Vr + m32 * 64 + ((ch ^ sw) << 3));
        o0 = __builtin_amdgcn_mfma_f32_32x32x16_bf16(pk, vf, o0, 0, 0, 0);
      }
      {
        bf16x8 vf = *(const bf16x8*)(Vr + (32 + m32) * 64 + ((ch ^ sw) << 3));
        o1 = __builtin_amdgcn_mfma_f32_32x32x16_bf16(pk, vf, o1, 0, 0, 0);
      }
      {
        bf16x8 vf = *(const bf16x8*)(Vr + (64 + m32) * 64 + ((ch ^ sw) << 3));
        o2 = __builtin_amdgcn_mfma_f32_32x32x16_bf16(pk, vf, o2, 0, 0, 0);
      }
      {
        bf16x8 vf = *(const bf16x8*)(Vr + (96 + m32) * 64 + ((ch ^ sw) << 3));
        o3 = __builtin_amdgcn_mfma_f32_32x32x16_bf16(pk, vf, o3, 0, 0, 0);
      }
    }
  };

  // prologue: tiles 0 and 1
  stage(Klds[0], Vlds[0]);
  __syncthreads();                 // tile 0 staged
  adv();
  stage(Klds[1], Vlds[1]);         // tile 1 in flight during QK(0)
  {
    f32x16 s0 = {}, s1 = {};
    qk(Klds[0], s0, s1);
    mkpa(s0, s1, pa0, pa1, pa2, pa3);
  }

  // main: t = 0..14 (PV(t), QK(t+1)); epilogue PV(15)
  for (int t = 0; t < 15; ++t) {
    int cur = t & 1, nxt = cur ^ 1;
    __syncthreads();               // barrier_A: tile t+1 staged (vmcnt drain)
    f32x16 s0 = {}, s1 = {};
    qk(Klds[nxt], s0, s1);         // QK(t+1)
    pv(Vlds[cur], pa0, pa1, pa2, pa3);   // PV(t) -- independent MFMA stream
    mkpa(s0, s1, pb0, pb1, pb2, pb3);    // exp(t+1) -- VALU fills MFMA drain
    __syncthreads();               // barrier_B: all waves done with buf[cur]
    if (t < 14) { adv(); stage(Klds[cur], Vlds[cur]); }   // tile t+2 -> cur
    pa0 = pb0; pa1 = pb1; pa2 = pb2; pa3 = pb3;
  }
  pv(Vlds[1], pa0, pa1, pa2, pa3);   // PV(15) (tile 15 lives in buffer 1)

  // store O normalized; lacc[reg] holds l for row (reg&3)+8*(reg>>2)+4*hf
  size_t obase = ((size_t)b * SEQ + qrow0) * DM + h * HDIM;
#pragma unroll
  for (int g = 0; g < 4; ++g) {
#pragma unroll
    for (int r = 0; r < 4; ++r) {
      int reg = 4 * g + r;
      int rowl = 8 * g + 4 * hf + r;
      float inv = 1.0f / lacc[reg];
      size_t off = obase + (size_t)rowl * DM + m32;
      CTX[off]      = f2b(o0[reg] * inv);
      CTX[off + 32] = f2b(o1[reg] * inv);
      CTX[off + 64] = f2b(o2[reg] * inv);
      CTX[off + 96] = f2b(o3[reg] * inv);
    }
  }
}

// ---------------------------------------------------------------------------
extern "C" void kernel_launch(void* const* d_in, const int* in_sizes, int n_in,
                              void* d_out, int out_size, void* d_ws, size_t ws_size,
                              hipStream_t stream) {
  const float* x1    = (const float*)d_in[0];
  const float* x2    = (const float*)d_in[1];
  const float* ln1_g = (const float*)d_in[2];
  const float* ln1_b = (const float*)d_in[3];
  const float* ln2_g = (const float*)d_in[4];
  const float* ln2_b = (const float*)d_in[5];
  const float* lnf_g = (const float*)d_in[6];
  const float* lnf_b = (const float*)d_in[7];
  P12 wsrc;
  for (int i = 0; i < 10; ++i) wsrc.p[i] = (const float*)d_in[8 + 2 * i];
  wsrc.p[10] = (const float*)d_in[28];   // W1
  wsrc.p[11] = (const float*)d_in[30];   // W2
  P9 bsrc;
  for (int i = 0; i < 9; ++i) bsrc.p[i] = (const float*)d_in[9 + 2 * i];
  const float* bo   = (const float*)d_in[27];
  const float* b1   = (const float*)d_in[29];
  const float* b2   = (const float*)d_in[31];

  char* ws = (char*)d_ws;
  size_t off = 0;
  auto alloc = [&](size_t bytes) -> char* {
    char* p = ws + off;
    off += (bytes + 255) & ~(size_t)255;
    return p;
  };
  unsigned short* WT0 = (unsigned short*)alloc((size_t)10 * 512 * 512 * 2);
  auto WT = [&](int i) { return WT0 + (size_t)i * 262144; };
  unsigned short* W1t = (unsigned short*)alloc((size_t)1024 * 512 * 2);
  unsigned short* W2t = (unsigned short*)alloc((size_t)512 * 1024 * 2);
  float*          bcc = (float*)alloc(4608 * 4);
  unsigned short* XN  = (unsigned short*)alloc((size_t)2 * MTOK * DM * 2);
  unsigned short* QKb = (unsigned short*)alloc((size_t)2 * MTOK * 1024 * 2);
  unsigned short* Vtb = (unsigned short*)alloc((size_t)128 * HDIM * SEQ * 2);
  unsigned short* CT  = (unsigned short*)alloc((size_t)2 * MTOK * DM * 2);
  float*          Xf  = (float*)alloc((size_t)MTOK * DM * 4);
  unsigned short* XN1 = XN + (size_t)MTOK * DM;
  unsigned short* MID = QKb;                       // alias (Q12/K12 dead)
  unsigned short* HN  = Vtb;                       // alias (Vt dead)
  float* bias_self  = bcc;                         // [2][1536]
  float* bias_cross = bcc + 3072;                  // [1536]

  // 0) prep: 12 weight transposes + bias concat, one dispatch
  prep_kernel<<<3602, 256, 0, stream>>>(wsrc, bsrc, WT0, W1t, W2t, bcc);

  // 1) both LayerNorms
  ln_kernel<<<2 * MTOK / 4, 256, 0, stream>>>(x1, x2, ln1_g, ln1_b, ln2_g, ln2_b, XN, XN1);

  // 2) self QKV, both streams, one dispatch: M=32768, N=1536 (Q pre-scaled)
  gemm_kernel<0, false, 3><<<3072, 256, 0, stream>>>(XN, nullptr, WT0, bias_self,
      nullptr, nullptr, QKb, Vtb, 32768, 1536, 512);

  // 3) self-attention, both streams: 128 pairs
  attn_kernel<<<128 * 8, 256, 0, stream>>>(QKb, QKb + 512, 1024, Vtb, CT, 16);

  // 4) out-proj + bias + residual(xn) -> src (in-place over XN, bf16)
  gemm_kernel<2, false, 0><<<1024, 256, 0, stream>>>(CT, nullptr, WT(9), bo, XN,
      nullptr, XN, nullptr, 32768, 512, 512);

  // 5) cross QKV, one dispatch: Q from src1(XN), K/V from src2(XN1)
  gemm_kernel<0, false, 4><<<1536, 256, 0, stream>>>(XN, XN1, WT(6), bias_cross,
      nullptr, nullptr, QKb, Vtb, 16384, 1536, 512);

  // 6) cross-attention: 64 pairs
  attn_kernel<<<64 * 8, 256, 0, stream>>>(QKb, QKb + (size_t)MTOK * 512, 512, Vtb, CT, 8);

  // 7) out-proj + bias + residual(identity x1, fp32) -> x (fp32)
  gemm_kernel<1, false, 1><<<512, 256, 0, stream>>>(CT, nullptr, WT(9), bo, x1,
      Xf, nullptr, nullptr, 16384, 512, 512);

  // 8) final LN
  ln_kernel<<<MTOK / 4, 256, 0, stream>>>(Xf, Xf, lnf_g, lnf_b, lnf_g, lnf_b, HN, HN);

  // 9) MLP: gelu(h@W1+b1) -> MID ; MID@W2+b2 + x -> out (fp32)
  gemm_kernel<0, true,  0><<<1024, 256, 0, stream>>>(HN, nullptr, W1t, b1,
      nullptr, nullptr, MID, nullptr, 16384, 1024, 512);
  gemm_kernel<1, false, 1><<<512, 256, 0, stream>>>(MID, nullptr, W2t, b2,
      Xf, (float*)d_out, nullptr, nullptr, 16384, 512, 1024);
}